// Round 4
// baseline (429.376 us; speedup 1.0000x reference)
//
#include <hip/hip_runtime.h>
#include <hip/hip_cooperative_groups.h>
#include <math.h>

namespace cg = cooperative_groups;

// Problem constants (match reference)
constexpr int Nn   = 8192;
constexpr int Ee   = 4096;
constexpr int DIN  = 256;
constexpr int DOUT = 128;
constexpr int NNZ  = 65536;
constexpr int EC   = 96;   // capacity: nodes per edge (deg ~ Poisson(16))
constexpr int NC   = 48;   // capacity: edges per node (deg ~ Poisson(8))
constexpr int NBLK = 256;  // cooperative grid: 1 block/CU -> capacity check cannot fail
constexpr int BLK  = 256;
constexpr int NWAV = NBLK * BLK / 64;   // 1024 waves

#define TEMPR 0.08838834764831845f   // 1/sqrt(128)
#define EM1   1.7182818284590452f    // e - 1

static __device__ __forceinline__ float wave_sum64(float v) {
#pragma unroll
    for (int m = 32; m; m >>= 1) v += __shfl_xor(v, m, 64);
    return v;
}
static __device__ __forceinline__ float wave_max64(float v) {
#pragma unroll
    for (int m = 32; m; m >>= 1) v = fmaxf(v, __shfl_xor(v, m, 64));
    return v;
}

struct Prm {
    const float* x; const float* W; const float* W2; const float* W3;
    const float* bias; const float* q; const int* hidx;
    void* zbase; unsigned zTotal16;
    unsigned* bitmap; int* degE; int* degN;
    float* wsArr; float* c2g;
    float* csx4; float* csxt; float* vxg; float* twxg; float* wsxg;
    float* x4; float* xt; float* rowv; float* vArr;
    int* csrEn; float* Sval; float* Tval; int* csrNe; int* csrNs;
    float* edgeF; float* G1; float* e4; float* G2;
    float* out;
};

union SMem {
    struct {                        // GEMM phases (37.5 KB)
        float sxT[32][36];
        float swA[32][128];
        float swB[32][128];
        float s4[DOUT];
        float st[DOUT];
    } g;
    struct {                        // edge phase per-wave scratch
        int   sN[4][EC];
        float sS[4][EC];
    } e;
    struct {                        // node2 reduction partials
        float a[DOUT]; float b[DOUT]; float c[DOUT];
    } r;
};

__global__ __launch_bounds__(BLK) void mega(Prm p)
{
    __shared__ SMem sm;
    cg::grid_group grid = cg::this_grid();

    const int t    = threadIdx.x;
    const int tx   = t & 31;
    const int ty   = t >> 5;
    const int lane = t & 63;
    const int w    = t >> 6;
    const unsigned gid = blockIdx.x * BLK + t;       // 0..65535
    const int wid  = gid >> 6;                        // 0..1023

    // ================= P0: zero bitmap + accumulators =======================
    {
        uint4 z; z.x = z.y = z.z = z.w = 0u;
        uint4* zp = (uint4*)p.zbase;
        for (unsigned i = gid; i < p.zTotal16; i += NBLK * BLK) zp[i] = z;
    }
    grid.sync();

    // ====== P1: build dedup'd CSR  +  P2: gemm1 (x4, xt + epilogues) ========
    {   // 65536 threads == NNZ
        const int n = p.hidx[gid];
        const int e = p.hidx[NNZ + gid];
        const unsigned word = (unsigned)n * (unsigned)Ee + (unsigned)e;
        const unsigned bit  = 1u << (word & 31u);
        const unsigned old  = atomicOr(&p.bitmap[word >> 5], bit);
        if (!(old & bit)) {
            const int pe = atomicAdd(&p.degE[e], 1);
            if (pe < EC) {
                p.csrEn[e * EC + pe] = n;
                const int pn = atomicAdd(&p.degN[n], 1);
                if (pn < NC) {
                    p.csrNe[n * NC + pn] = e;
                    p.csrNs[n * NC + pn] = e * EC + pe;
                }
            }
        }
    }
    {   // gemm1: 32-row tile per block (256 blocks x 32 = 8192 rows)
        const int r0 = blockIdx.x * 32;
        float accA[4][4], accB[4][4];
#pragma unroll
        for (int r = 0; r < 4; ++r)
#pragma unroll
            for (int c = 0; c < 4; ++c) { accA[r][c] = 0.f; accB[r][c] = 0.f; }

        for (int k0 = 0; k0 < DIN; k0 += 32) {
            __syncthreads();
            {
                const int row = t & 31;
                const int kq  = (t >> 5) * 4;
                const float4 v0 = *(const float4*)&p.x[(size_t)(r0 + row) * DIN + k0 + kq];
                sm.g.sxT[kq + 0][row] = v0.x; sm.g.sxT[kq + 1][row] = v0.y;
                sm.g.sxT[kq + 2][row] = v0.z; sm.g.sxT[kq + 3][row] = v0.w;
            }
#pragma unroll
            for (int i = 0; i < 4; ++i) {
                const int idx = t + i * 256;
                const int kr  = idx >> 5;
                const int c4  = (idx & 31) * 4;
                *(float4*)&sm.g.swA[kr][c4] = *(const float4*)&p.W [(size_t)(k0 + kr) * DOUT + c4];
                *(float4*)&sm.g.swB[kr][c4] = *(const float4*)&p.W2[(size_t)(k0 + kr) * DOUT + c4];
            }
            __syncthreads();
#pragma unroll
            for (int kk = 0; kk < 32; ++kk) {
                const float4 a  = *(const float4*)&sm.g.sxT[kk][ty * 4];
                const float4 bA = *(const float4*)&sm.g.swA[kk][tx * 4];
                const float4 bB = *(const float4*)&sm.g.swB[kk][tx * 4];
                const float av[4]  = {a.x,  a.y,  a.z,  a.w};
                const float bAv[4] = {bA.x, bA.y, bA.z, bA.w};
                const float bBv[4] = {bB.x, bB.y, bB.z, bB.w};
#pragma unroll
                for (int r = 0; r < 4; ++r)
#pragma unroll
                    for (int c = 0; c < 4; ++c) {
                        accA[r][c] = fmaf(av[r], bAv[c], accA[r][c]);
                        accB[r][c] = fmaf(av[r], bBv[c], accB[r][c]);
                    }
            }
        }
        const float4 b4 = *(const float4*)&p.bias[tx * 4];
        const float4 q4 = *(const float4*)&p.q[tx * 4];
#pragma unroll
        for (int r = 0; r < 4; ++r) {
            const int row = r0 + ty * 4 + r;
            float4 o;
            o.x = accB[r][0]; o.y = accB[r][1]; o.z = accB[r][2]; o.w = accB[r][3];
            *(float4*)&p.x4[(size_t)row * DOUT + tx * 4] = o;
            o.x = accA[r][0] + b4.x; o.y = accA[r][1] + b4.y;
            o.z = accA[r][2] + b4.z; o.w = accA[r][3] + b4.w;
            *(float4*)&p.xt[(size_t)row * DOUT + tx * 4] = o;
        }
        float pr[4];
#pragma unroll
        for (int r = 0; r < 4; ++r)
            pr[r] = accB[r][0]*q4.x + accB[r][1]*q4.y + accB[r][2]*q4.z + accB[r][3]*q4.w;
#pragma unroll
        for (int m = 16; m; m >>= 1) {
#pragma unroll
            for (int r = 0; r < 4; ++r) pr[r] += __shfl_xor(pr[r], m, 64);
        }
        if (tx == 0) {
#pragma unroll
            for (int r = 0; r < 4; ++r) p.rowv[r0 + ty * 4 + r] = pr[r] * TEMPR;
        }
        if (t < DOUT) { sm.g.s4[t] = 0.f; sm.g.st[t] = 0.f; }
        __syncthreads();
        const float b4v[4] = {b4.x, b4.y, b4.z, b4.w};
#pragma unroll
        for (int c = 0; c < 4; ++c) {
            float p4 = accB[0][c] + accB[1][c] + accB[2][c] + accB[3][c];
            float pt = accA[0][c] + accA[1][c] + accA[2][c] + accA[3][c] + 4.f * b4v[c];
            atomicAdd(&sm.g.s4[tx * 4 + c], p4);
            atomicAdd(&sm.g.st[tx * 4 + c], pt);
        }
        __syncthreads();
        if (t < DOUT) { atomicAdd(&p.csx4[t], sm.g.s4[t]); atomicAdd(&p.csxt[t], sm.g.st[t]); }
    }
    grid.sync();

    // ====== P3: per-edge softmax1 + gather (edgeF, G1) + ws scatter =========
    for (int s = 0; s < Ee / NWAV; ++s) {
        const int e   = wid + s * NWAV;
        const int deg = min(p.degE[e], EC);
        const float ue = deg ? 1.0f / ((float)Nn + (float)deg * EM1) : 2.0f / (float)Nn;
        int   n0 = 0, n1 = 0;
        float r0 = -INFINITY, r1 = -INFINITY;
        if (lane < deg)      { n0 = p.csrEn[e * EC + lane];      r0 = p.rowv[n0]; }
        if (lane + 64 < deg) { n1 = p.csrEn[e * EC + lane + 64]; r1 = p.rowv[n1]; }
        const float m  = wave_max64(fmaxf(r0, r1));
        const float e0 = (lane < deg)      ? expf(r0 - m) : 0.f;
        const float e1 = (lane + 64 < deg) ? expf(r1 - m) : 0.f;
        const float Z  = wave_sum64(e0 + e1);
        const float inv = deg ? 1.0f / Z : 0.f;
        const float base = EM1 * ue;
        if (lane < deg) {
            const float sv = fmaf(e0, inv, base);
            sm.e.sN[w][lane] = n0; sm.e.sS[w][lane] = sv;
            p.Sval[e * EC + lane] = sv;
            atomicAdd(&p.wsArr[n0], ue * sv);
        }
        if (lane + 64 < deg) {
            const float sv = fmaf(e1, inv, base);
            sm.e.sN[w][lane + 64] = n1; sm.e.sS[w][lane + 64] = sv;
            p.Sval[e * EC + lane + 64] = sv;
            atomicAdd(&p.wsArr[n1], ue * sv);
        }
        const float2 ct = *(const float2*)&p.csxt[lane * 2];
        const float2 c4 = *(const float2*)&p.csx4[lane * 2];
        float2 aE = make_float2(ue * ct.x, ue * ct.y);
        float2 aG = make_float2(ue * c4.x, ue * c4.y);
        int j = 0;
        for (; j + 4 <= deg; j += 4) {
            const int a0 = sm.e.sN[w][j+0], a1 = sm.e.sN[w][j+1];
            const int a2 = sm.e.sN[w][j+2], a3 = sm.e.sN[w][j+3];
            const float b0 = sm.e.sS[w][j+0], b1 = sm.e.sS[w][j+1];
            const float b2 = sm.e.sS[w][j+2], b3 = sm.e.sS[w][j+3];
            const float2 t0 = *(const float2*)&p.xt[(size_t)a0 * DOUT + lane * 2];
            const float2 f0 = *(const float2*)&p.x4[(size_t)a0 * DOUT + lane * 2];
            const float2 t1 = *(const float2*)&p.xt[(size_t)a1 * DOUT + lane * 2];
            const float2 f1 = *(const float2*)&p.x4[(size_t)a1 * DOUT + lane * 2];
            const float2 t2 = *(const float2*)&p.xt[(size_t)a2 * DOUT + lane * 2];
            const float2 f2 = *(const float2*)&p.x4[(size_t)a2 * DOUT + lane * 2];
            const float2 t3 = *(const float2*)&p.xt[(size_t)a3 * DOUT + lane * 2];
            const float2 f3 = *(const float2*)&p.x4[(size_t)a3 * DOUT + lane * 2];
            aE.x = fmaf(b0, t0.x, aE.x); aE.y = fmaf(b0, t0.y, aE.y);
            aG.x = fmaf(b0, f0.x, aG.x); aG.y = fmaf(b0, f0.y, aG.y);
            aE.x = fmaf(b1, t1.x, aE.x); aE.y = fmaf(b1, t1.y, aE.y);
            aG.x = fmaf(b1, f1.x, aG.x); aG.y = fmaf(b1, f1.y, aG.y);
            aE.x = fmaf(b2, t2.x, aE.x); aE.y = fmaf(b2, t2.y, aE.y);
            aG.x = fmaf(b2, f2.x, aG.x); aG.y = fmaf(b2, f2.y, aG.y);
            aE.x = fmaf(b3, t3.x, aE.x); aE.y = fmaf(b3, t3.y, aE.y);
            aG.x = fmaf(b3, f3.x, aG.x); aG.y = fmaf(b3, f3.y, aG.y);
        }
        for (; j < deg; ++j) {
            const int   a = sm.e.sN[w][j];
            const float b = sm.e.sS[w][j];
            const float2 tv = *(const float2*)&p.xt[(size_t)a * DOUT + lane * 2];
            const float2 fv = *(const float2*)&p.x4[(size_t)a * DOUT + lane * 2];
            aE.x = fmaf(b, tv.x, aE.x); aE.y = fmaf(b, tv.y, aE.y);
            aG.x = fmaf(b, fv.x, aG.x); aG.y = fmaf(b, fv.y, aG.y);
        }
        *(float2*)&p.edgeF[(size_t)e * DOUT + lane * 2] = aE;
        *(float2*)&p.G1  [(size_t)e * DOUT + lane * 2] = aG;
    }
    grid.sync();

    // ====== P4: e4 = edgeF @ W3  (blocks 0..127, 32-row tiles) ==============
    if (blockIdx.x < Ee / 32) {
        const int r0 = blockIdx.x * 32;
        float acc[4][4];
#pragma unroll
        for (int r = 0; r < 4; ++r)
#pragma unroll
            for (int c = 0; c < 4; ++c) acc[r][c] = 0.f;
        for (int k0 = 0; k0 < DOUT; k0 += 32) {
            __syncthreads();
            {
                const int row = t & 31;
                const int kq  = (t >> 5) * 4;
                const float4 v0 = *(const float4*)&p.edgeF[(size_t)(r0 + row) * DOUT + k0 + kq];
                sm.g.sxT[kq + 0][row] = v0.x; sm.g.sxT[kq + 1][row] = v0.y;
                sm.g.sxT[kq + 2][row] = v0.z; sm.g.sxT[kq + 3][row] = v0.w;
            }
#pragma unroll
            for (int i = 0; i < 4; ++i) {
                const int idx = t + i * 256;
                const int kr  = idx >> 5;
                const int c4  = (idx & 31) * 4;
                *(float4*)&sm.g.swA[kr][c4] = *(const float4*)&p.W3[(size_t)(k0 + kr) * DOUT + c4];
            }
            __syncthreads();
#pragma unroll
            for (int kk = 0; kk < 32; ++kk) {
                const float4 a = *(const float4*)&sm.g.sxT[kk][ty * 4];
                const float4 b = *(const float4*)&sm.g.swA[kk][tx * 4];
                const float av[4] = {a.x, a.y, a.z, a.w};
                const float bv[4] = {b.x, b.y, b.z, b.w};
#pragma unroll
                for (int r = 0; r < 4; ++r)
#pragma unroll
                    for (int c = 0; c < 4; ++c)
                        acc[r][c] = fmaf(av[r], bv[c], acc[r][c]);
            }
        }
#pragma unroll
        for (int r = 0; r < 4; ++r) {
            const int row = r0 + ty * 4 + r;
            float4 o;
            o.x = acc[r][0]; o.y = acc[r][1]; o.z = acc[r][2]; o.w = acc[r][3];
            *(float4*)&p.e4[(size_t)row * DOUT + tx * 4] = o;
        }
    }
    grid.sync();

    // ====== P5: per-node softmax2 -> Tval, v[n]; weighted colsum epilogue ===
    {
        float2 vxa = {0,0}, twa = {0,0}, wsa = {0,0};
        for (int s = 0; s < Nn / NWAV; ++s) {
            const int n   = wid + s * NWAV;
            const int deg = min(p.degN[n], NC);
            const float vn = deg ? 1.0f / ((float)Ee + (float)deg * EM1) : 2.0f / (float)Ee;
            const float2 xv = *(const float2*)&p.x4[(size_t)n * DOUT + lane * 2];
            float m = -INFINITY, skeep = 0.f;
            int j = 0;
            for (; j + 2 <= deg; j += 2) {
                const int ea = p.csrNe[n * NC + j];
                const int eb = p.csrNe[n * NC + j + 1];
                const float2 eva = *(const float2*)&p.e4[(size_t)ea * DOUT + lane * 2];
                const float2 evb = *(const float2*)&p.e4[(size_t)eb * DOUT + lane * 2];
                float pa = fmaf(xv.x, eva.x, xv.y * eva.y);
                float pb = fmaf(xv.x, evb.x, xv.y * evb.y);
#pragma unroll
                for (int mm = 32; mm; mm >>= 1) {
                    pa += __shfl_xor(pa, mm, 64);
                    pb += __shfl_xor(pb, mm, 64);
                }
                pa *= TEMPR; pb *= TEMPR;
                m = fmaxf(m, fmaxf(pa, pb));
                if (lane == j)     skeep = pa;
                if (lane == j + 1) skeep = pb;
            }
            if (j < deg) {
                const int ea = p.csrNe[n * NC + j];
                const float2 eva = *(const float2*)&p.e4[(size_t)ea * DOUT + lane * 2];
                float pa = fmaf(xv.x, eva.x, xv.y * eva.y);
                pa = wave_sum64(pa) * TEMPR;
                m = fmaxf(m, pa);
                if (lane == j) skeep = pa;
            }
            const float ex = (lane < deg) ? expf(skeep - m) : 0.f;
            const float Z  = wave_sum64(ex);
            if (lane < deg) p.Tval[p.csrNs[n * NC + lane]] = fmaf(EM1, vn, ex / Z);
            if (lane == 0) p.vArr[n] = vn;
            const float tw  = deg ? fmaf((float)deg * EM1, vn, 1.0f) : 0.f;
            const float wsn = p.wsArr[n];
            vxa.x = fmaf(vn,  xv.x, vxa.x); vxa.y = fmaf(vn,  xv.y, vxa.y);
            twa.x = fmaf(tw,  xv.x, twa.x); twa.y = fmaf(tw,  xv.y, twa.y);
            wsa.x = fmaf(wsn, xv.x, wsa.x); wsa.y = fmaf(wsn, xv.y, wsa.y);
        }
        __syncthreads();
        if (t < DOUT) { sm.r.a[t] = 0.f; sm.r.b[t] = 0.f; sm.r.c[t] = 0.f; }
        __syncthreads();
        atomicAdd(&sm.r.a[lane*2+0], vxa.x); atomicAdd(&sm.r.a[lane*2+1], vxa.y);
        atomicAdd(&sm.r.b[lane*2+0], twa.x); atomicAdd(&sm.r.b[lane*2+1], twa.y);
        atomicAdd(&sm.r.c[lane*2+0], wsa.x); atomicAdd(&sm.r.c[lane*2+1], wsa.y);
        __syncthreads();
        if (t < DOUT) {
            atomicAdd(&p.vxg[t],  sm.r.a[t]);
            atomicAdd(&p.twxg[t], sm.r.b[t]);
            atomicAdd(&p.wsxg[t], sm.r.c[t]);
        }
    }
    grid.sync();

    // ====== P6: c2 reduction + per-edge G2 gather ===========================
    {
        float c2p = 0.f;
        if (gid < (unsigned)Ee) {
            const int dg = min(p.degE[gid], EC);
            const float ue = dg ? 1.0f / ((float)Nn + (float)dg * EM1) : 2.0f / (float)Nn;
            c2p = ue * ue;
        }
        c2p = wave_sum64(c2p);
        if (lane == 0 && c2p != 0.f) atomicAdd(p.c2g, c2p);
    }
    for (int s = 0; s < Ee / NWAV; ++s) {
        const int e   = wid + s * NWAV;
        const int deg = min(p.degE[e], EC);
        float2 acc = *(const float2*)&p.vxg[lane * 2];
        int j = 0;
        for (; j + 4 <= deg; j += 4) {
            const int a0 = p.csrEn[e*EC+j+0], a1 = p.csrEn[e*EC+j+1];
            const int a2 = p.csrEn[e*EC+j+2], a3 = p.csrEn[e*EC+j+3];
            const float b0 = p.Tval[e*EC+j+0], b1 = p.Tval[e*EC+j+1];
            const float b2 = p.Tval[e*EC+j+2], b3 = p.Tval[e*EC+j+3];
            const float2 f0 = *(const float2*)&p.x4[(size_t)a0 * DOUT + lane * 2];
            const float2 f1 = *(const float2*)&p.x4[(size_t)a1 * DOUT + lane * 2];
            const float2 f2 = *(const float2*)&p.x4[(size_t)a2 * DOUT + lane * 2];
            const float2 f3 = *(const float2*)&p.x4[(size_t)a3 * DOUT + lane * 2];
            acc.x = fmaf(b0, f0.x, acc.x); acc.y = fmaf(b0, f0.y, acc.y);
            acc.x = fmaf(b1, f1.x, acc.x); acc.y = fmaf(b1, f1.y, acc.y);
            acc.x = fmaf(b2, f2.x, acc.x); acc.y = fmaf(b2, f2.y, acc.y);
            acc.x = fmaf(b3, f3.x, acc.x); acc.y = fmaf(b3, f3.y, acc.y);
        }
        for (; j < deg; ++j) {
            const int   a = p.csrEn[e*EC+j];
            const float b = p.Tval[e*EC+j];
            const float2 fv = *(const float2*)&p.x4[(size_t)a * DOUT + lane * 2];
            acc.x = fmaf(b, fv.x, acc.x); acc.y = fmaf(b, fv.y, acc.y);
        }
        *(float2*)&p.G2[(size_t)e * DOUT + lane * 2] = acc;
    }
    grid.sync();

    // ====== P7: final combine + elu =========================================
    {
        const float c2 = *p.c2g;
        const float2 c4v = *(const float2*)&p.csx4[lane * 2];
        const float2 wsv = *(const float2*)&p.wsxg[lane * 2];
        const float2 vxv = *(const float2*)&p.vxg[lane * 2];
        const float2 twv = *(const float2*)&p.twxg[lane * 2];
        for (int s = 0; s < Nn / NWAV; ++s) {
            const int n   = wid + s * NWAV;
            const int deg = min(p.degN[n], NC);
            const float vn = p.vArr[n];
            float2 acc;
            acc.x = fmaf(c2, c4v.x, wsv.x) + vn * fmaf((float)Ee, vxv.x, twv.x);
            acc.y = fmaf(c2, c4v.y, wsv.y) + vn * fmaf((float)Ee, vxv.y, twv.y);
            int j = 0;
            for (; j + 2 <= deg; j += 2) {
                const int ea = p.csrNe[n*NC+j],   eb = p.csrNe[n*NC+j+1];
                const int sa = p.csrNs[n*NC+j],   sb = p.csrNs[n*NC+j+1];
                const float sva = p.Sval[sa], tva = p.Tval[sa];
                const float svb = p.Sval[sb], tvb = p.Tval[sb];
                const float2 g1a = *(const float2*)&p.G1[(size_t)ea * DOUT + lane * 2];
                const float2 g2a = *(const float2*)&p.G2[(size_t)ea * DOUT + lane * 2];
                const float2 g1b = *(const float2*)&p.G1[(size_t)eb * DOUT + lane * 2];
                const float2 g2b = *(const float2*)&p.G2[(size_t)eb * DOUT + lane * 2];
                acc.x = fmaf(sva, g1a.x, acc.x); acc.y = fmaf(sva, g1a.y, acc.y);
                acc.x = fmaf(tva, g2a.x, acc.x); acc.y = fmaf(tva, g2a.y, acc.y);
                acc.x = fmaf(svb, g1b.x, acc.x); acc.y = fmaf(svb, g1b.y, acc.y);
                acc.x = fmaf(tvb, g2b.x, acc.x); acc.y = fmaf(tvb, g2b.y, acc.y);
            }
            for (; j < deg; ++j) {
                const int ea = p.csrNe[n*NC+j];
                const int sa = p.csrNs[n*NC+j];
                const float sva = p.Sval[sa], tva = p.Tval[sa];
                const float2 g1a = *(const float2*)&p.G1[(size_t)ea * DOUT + lane * 2];
                const float2 g2a = *(const float2*)&p.G2[(size_t)ea * DOUT + lane * 2];
                acc.x = fmaf(sva, g1a.x, acc.x); acc.y = fmaf(sva, g1a.y, acc.y);
                acc.x = fmaf(tva, g2a.x, acc.x); acc.y = fmaf(tva, g2a.y, acc.y);
            }
            acc.x = acc.x > 0.f ? acc.x : expm1f(acc.x);
            acc.y = acc.y > 0.f ? acc.y : expm1f(acc.y);
            *(float2*)&p.out[(size_t)n * DOUT + lane * 2] = acc;
        }
    }
}

// ===========================================================================
// Fallback pipeline (Round-2 proven kernels), used if cooperative launch fails
// ===========================================================================
__global__ __launch_bounds__(256) void k_gemm1f(
    const float* __restrict__ x, const float* __restrict__ W,
    const float* __restrict__ W2, const float* __restrict__ bias,
    const float* __restrict__ q,
    float* __restrict__ x4, float* __restrict__ xt,
    float* __restrict__ rowv, float* __restrict__ csx4, float* __restrict__ csxt)
{
    __shared__ float sxT[32][36];
    __shared__ float swA[32][128];
    __shared__ float swB[32][128];
    __shared__ float s4[DOUT], st[DOUT];
    const int t  = threadIdx.x;
    const int tx = t & 31;
    const int ty = t >> 5;
    const int r0 = blockIdx.x * 32;

    float accA[4][4], accB[4][4];
#pragma unroll
    for (int r = 0; r < 4; ++r)
#pragma unroll
        for (int c = 0; c < 4; ++c) { accA[r][c] = 0.f; accB[r][c] = 0.f; }

    for (int k0 = 0; k0 < DIN; k0 += 32) {
        __syncthreads();
        {
            const int row = t & 31;
            const int kq  = (t >> 5) * 4;
            const float4 v0 = *(const float4*)&x[(size_t)(r0 + row) * DIN + k0 + kq];
            sxT[kq + 0][row] = v0.x; sxT[kq + 1][row] = v0.y;
            sxT[kq + 2][row] = v0.z; sxT[kq + 3][row] = v0.w;
        }
#pragma unroll
        for (int i = 0; i < 4; ++i) {
            const int idx = t + i * 256;
            const int kr  = idx >> 5;
            const int c4  = (idx & 31) * 4;
            *(float4*)&swA[kr][c4] = *(const float4*)&W [(size_t)(k0 + kr) * DOUT + c4];
            *(float4*)&swB[kr][c4] = *(const float4*)&W2[(size_t)(k0 + kr) * DOUT + c4];
        }
        __syncthreads();
#pragma unroll
        for (int kk = 0; kk < 32; ++kk) {
            const float4 a  = *(const float4*)&sxT[kk][ty * 4];
            const float4 bA = *(const float4*)&swA[kk][tx * 4];
            const float4 bB = *(const float4*)&swB[kk][tx * 4];
            const float av[4]  = {a.x,  a.y,  a.z,  a.w};
            const float bAv[4] = {bA.x, bA.y, bA.z, bA.w};
            const float bBv[4] = {bB.x, bB.y, bB.z, bB.w};
#pragma unroll
            for (int r = 0; r < 4; ++r)
#pragma unroll
                for (int c = 0; c < 4; ++c) {
                    accA[r][c] = fmaf(av[r], bAv[c], accA[r][c]);
                    accB[r][c] = fmaf(av[r], bBv[c], accB[r][c]);
                }
        }
    }
    const float4 b4 = *(const float4*)&bias[tx * 4];
    const float4 q4 = *(const float4*)&q[tx * 4];
#pragma unroll
    for (int r = 0; r < 4; ++r) {
        const int row = r0 + ty * 4 + r;
        float4 o;
        o.x = accB[r][0]; o.y = accB[r][1]; o.z = accB[r][2]; o.w = accB[r][3];
        *(float4*)&x4[(size_t)row * DOUT + tx * 4] = o;
        o.x = accA[r][0] + b4.x; o.y = accA[r][1] + b4.y;
        o.z = accA[r][2] + b4.z; o.w = accA[r][3] + b4.w;
        *(float4*)&xt[(size_t)row * DOUT + tx * 4] = o;
    }
    float pr[4];
#pragma unroll
    for (int r = 0; r < 4; ++r)
        pr[r] = accB[r][0]*q4.x + accB[r][1]*q4.y + accB[r][2]*q4.z + accB[r][3]*q4.w;
#pragma unroll
    for (int m = 16; m; m >>= 1) {
#pragma unroll
        for (int r = 0; r < 4; ++r) pr[r] += __shfl_xor(pr[r], m, 64);
    }
    if (tx == 0) {
#pragma unroll
        for (int r = 0; r < 4; ++r) rowv[r0 + ty * 4 + r] = pr[r] * TEMPR;
    }
    if (t < DOUT) { s4[t] = 0.f; st[t] = 0.f; }
    __syncthreads();
    const float b4v[4] = {b4.x, b4.y, b4.z, b4.w};
#pragma unroll
    for (int c = 0; c < 4; ++c) {
        float p4 = accB[0][c] + accB[1][c] + accB[2][c] + accB[3][c];
        float pt = accA[0][c] + accA[1][c] + accA[2][c] + accA[3][c] + 4.f * b4v[c];
        atomicAdd(&s4[tx * 4 + c], p4);
        atomicAdd(&st[tx * 4 + c], pt);
    }
    __syncthreads();
    if (t < DOUT) { atomicAdd(&csx4[t], s4[t]); atomicAdd(&csxt[t], st[t]); }
}

__global__ __launch_bounds__(256) void k_build(
    const int* __restrict__ hidx, unsigned* __restrict__ bitmap,
    int* __restrict__ degE, int* __restrict__ degN,
    int* __restrict__ csrEn, int* __restrict__ csrNe, int* __restrict__ csrNs)
{
    const int k = blockIdx.x * 256 + threadIdx.x;
    const int n = hidx[k];
    const int e = hidx[NNZ + k];
    const unsigned word = (unsigned)n * (unsigned)Ee + (unsigned)e;
    const unsigned bit  = 1u << (word & 31u);
    const unsigned old  = atomicOr(&bitmap[word >> 5], bit);
    if (!(old & bit)) {
        const int pe = atomicAdd(&degE[e], 1);
        if (pe < EC) {
            csrEn[e * EC + pe] = n;
            const int pn = atomicAdd(&degN[n], 1);
            if (pn < NC) {
                csrNe[n * NC + pn] = e;
                csrNs[n * NC + pn] = e * EC + pe;
            }
        }
    }
}

__global__ __launch_bounds__(256) void k_edge1(
    const int* __restrict__ degE, const int* __restrict__ csrEn,
    const float* __restrict__ rowv,
    const float* __restrict__ csx4, const float* __restrict__ csxt,
    const float* __restrict__ x4, const float* __restrict__ xt,
    float* __restrict__ Sval, float* __restrict__ edgeF, float* __restrict__ G1,
    float* __restrict__ wsArr, float* __restrict__ c2g)
{
    __shared__ int   sN[4][EC];
    __shared__ float sS[4][EC];
    __shared__ float sC2[4];
    const int t    = threadIdx.x;
    const int w    = t >> 6;
    const int lane = t & 63;
    const int e    = blockIdx.x * 4 + w;
    const int deg  = min(degE[e], EC);
    const float ue = deg ? 1.0f / ((float)Nn + (float)deg * EM1) : 2.0f / (float)Nn;

    int   n0 = 0, n1 = 0;
    float r0 = -INFINITY, r1 = -INFINITY;
    if (lane < deg)      { n0 = csrEn[e * EC + lane];      r0 = rowv[n0]; }
    if (lane + 64 < deg) { n1 = csrEn[e * EC + lane + 64]; r1 = rowv[n1]; }
    const float m  = wave_max64(fmaxf(r0, r1));
    const float e0 = (lane < deg)      ? expf(r0 - m) : 0.f;
    const float e1 = (lane + 64 < deg) ? expf(r1 - m) : 0.f;
    const float Z  = wave_sum64(e0 + e1);
    const float inv = deg ? 1.0f / Z : 0.f;
    const float base = EM1 * ue;
    if (lane < deg) {
        const float sv = fmaf(e0, inv, base);
        sN[w][lane] = n0; sS[w][lane] = sv;
        Sval[e * EC + lane] = sv;
        atomicAdd(&wsArr[n0], ue * sv);
    }
    if (lane + 64 < deg) {
        const float sv = fmaf(e1, inv, base);
        sN[w][lane + 64] = n1; sS[w][lane + 64] = sv;
        Sval[e * EC + lane + 64] = sv;
        atomicAdd(&wsArr[n1], ue * sv);
    }
    const float2 ct = *(const float2*)&csxt[lane * 2];
    const float2 c4 = *(const float2*)&csx4[lane * 2];
    float2 aE = make_float2(ue * ct.x, ue * ct.y);
    float2 aG = make_float2(ue * c4.x, ue * c4.y);
    int j = 0;
    for (; j + 4 <= deg; j += 4) {
        const int a0 = sN[w][j+0], a1 = sN[w][j+1], a2 = sN[w][j+2], a3 = sN[w][j+3];
        const float b0 = sS[w][j+0], b1 = sS[w][j+1], b2 = sS[w][j+2], b3 = sS[w][j+3];
        const float2 t0 = *(const float2*)&xt[(size_t)a0 * DOUT + lane * 2];
        const float2 f0 = *(const float2*)&x4[(size_t)a0 * DOUT + lane * 2];
        const float2 t1 = *(const float2*)&xt[(size_t)a1 * DOUT + lane * 2];
        const float2 f1 = *(const float2*)&x4[(size_t)a1 * DOUT + lane * 2];
        const float2 t2 = *(const float2*)&xt[(size_t)a2 * DOUT + lane * 2];
        const float2 f2 = *(const float2*)&x4[(size_t)a2 * DOUT + lane * 2];
        const float2 t3 = *(const float2*)&xt[(size_t)a3 * DOUT + lane * 2];
        const float2 f3 = *(const float2*)&x4[(size_t)a3 * DOUT + lane * 2];
        aE.x = fmaf(b0, t0.x, aE.x); aE.y = fmaf(b0, t0.y, aE.y);
        aG.x = fmaf(b0, f0.x, aG.x); aG.y = fmaf(b0, f0.y, aG.y);
        aE.x = fmaf(b1, t1.x, aE.x); aE.y = fmaf(b1, t1.y, aE.y);
        aG.x = fmaf(b1, f1.x, aG.x); aG.y = fmaf(b1, f1.y, aG.y);
        aE.x = fmaf(b2, t2.x, aE.x); aE.y = fmaf(b2, t2.y, aE.y);
        aG.x = fmaf(b2, f2.x, aG.x); aG.y = fmaf(b2, f2.y, aG.y);
        aE.x = fmaf(b3, t3.x, aE.x); aE.y = fmaf(b3, t3.y, aE.y);
        aG.x = fmaf(b3, f3.x, aG.x); aG.y = fmaf(b3, f3.y, aG.y);
    }
    for (; j < deg; ++j) {
        const int   a = sN[w][j];
        const float b = sS[w][j];
        const float2 tv = *(const float2*)&xt[(size_t)a * DOUT + lane * 2];
        const float2 fv = *(const float2*)&x4[(size_t)a * DOUT + lane * 2];
        aE.x = fmaf(b, tv.x, aE.x); aE.y = fmaf(b, tv.y, aE.y);
        aG.x = fmaf(b, fv.x, aG.x); aG.y = fmaf(b, fv.y, aG.y);
    }
    *(float2*)&edgeF[(size_t)e * DOUT + lane * 2] = aE;
    *(float2*)&G1  [(size_t)e * DOUT + lane * 2] = aG;

    if (lane == 0) sC2[w] = ue * ue;
    __syncthreads();
    if (t == 0) atomicAdd(c2g, sC2[0] + sC2[1] + sC2[2] + sC2[3]);
}

__global__ __launch_bounds__(256) void k_gemm3(
    const float* __restrict__ A, const float* __restrict__ W3,
    float* __restrict__ C)
{
    __shared__ float sxT[32][36];
    __shared__ float sw[32][128];
    const int t  = threadIdx.x;
    const int tx = t & 31;
    const int ty = t >> 5;
    const int r0 = blockIdx.x * 32;
    float acc[4][4];
#pragma unroll
    for (int r = 0; r < 4; ++r)
#pragma unroll
        for (int c = 0; c < 4; ++c) acc[r][c] = 0.f;

    for (int k0 = 0; k0 < DOUT; k0 += 32) {
        __syncthreads();
        {
            const int row = t & 31;
            const int kq  = (t >> 5) * 4;
            const float4 v0 = *(const float4*)&A[(size_t)(r0 + row) * DOUT + k0 + kq];
            sxT[kq + 0][row] = v0.x; sxT[kq + 1][row] = v0.y;
            sxT[kq + 2][row] = v0.z; sxT[kq + 3][row] = v0.w;
        }
#pragma unroll
        for (int i = 0; i < 4; ++i) {
            const int idx = t + i * 256;
            const int kr  = idx >> 5;
            const int c4  = (idx & 31) * 4;
            *(float4*)&sw[kr][c4] = *(const float4*)&W3[(size_t)(k0 + kr) * DOUT + c4];
        }
        __syncthreads();
#pragma unroll
        for (int kk = 0; kk < 32; ++kk) {
            const float4 a = *(const float4*)&sxT[kk][ty * 4];
            const float4 b = *(const float4*)&sw[kk][tx * 4];
            const float av[4] = {a.x, a.y, a.z, a.w};
            const float bv[4] = {b.x, b.y, b.z, b.w};
#pragma unroll
            for (int r = 0; r < 4; ++r)
#pragma unroll
                for (int c = 0; c < 4; ++c)
                    acc[r][c] = fmaf(av[r], bv[c], acc[r][c]);
        }
    }
#pragma unroll
    for (int r = 0; r < 4; ++r) {
        const int row = r0 + ty * 4 + r;
        float4 o;
        o.x = acc[r][0]; o.y = acc[r][1]; o.z = acc[r][2]; o.w = acc[r][3];
        *(float4*)&C[(size_t)row * DOUT + tx * 4] = o;
    }
}

__global__ __launch_bounds__(256) void k_node2(
    const int* __restrict__ degN, const int* __restrict__ csrNe,
    const int* __restrict__ csrNs, const float* __restrict__ x4,
    const float* __restrict__ e4, const float* __restrict__ wsArr,
    float* __restrict__ Tval, float* __restrict__ vArr,
    float* __restrict__ vxg, float* __restrict__ twxg, float* __restrict__ wsxg)
{
    __shared__ float sVX[DOUT], sTX[DOUT], sWX[DOUT];
    const int t    = threadIdx.x;
    const int w    = t >> 6;
    const int lane = t & 63;
    const int nb   = blockIdx.x * 16 + w * 4;

    float2 vxa = {0,0}, twa = {0,0}, wsa = {0,0};
    for (int s = 0; s < 4; ++s) {
        const int n   = nb + s;
        const int deg = min(degN[n], NC);
        const float vn = deg ? 1.0f / ((float)Ee + (float)deg * EM1) : 2.0f / (float)Ee;
        const float2 xv = *(const float2*)&x4[(size_t)n * DOUT + lane * 2];
        float m = -INFINITY, skeep = 0.f;
        int j = 0;
        for (; j + 2 <= deg; j += 2) {
            const int ea = csrNe[n * NC + j];
            const int eb = csrNe[n * NC + j + 1];
            const float2 eva = *(const float2*)&e4[(size_t)ea * DOUT + lane * 2];
            const float2 evb = *(const float2*)&e4[(size_t)eb * DOUT + lane * 2];
            float pa = fmaf(xv.x, eva.x, xv.y * eva.y);
            float pb = fmaf(xv.x, evb.x, xv.y * evb.y);
#pragma unroll
            for (int mm = 32; mm; mm >>= 1) {
                pa += __shfl_xor(pa, mm, 64);
                pb += __shfl_xor(pb, mm, 64);
            }
            pa *= TEMPR; pb *= TEMPR;
            m = fmaxf(m, fmaxf(pa, pb));
            if (lane == j)     skeep = pa;
            if (lane == j + 1) skeep = pb;
        }
        if (j < deg) {
            const int ea = csrNe[n * NC + j];
            const float2 eva = *(const float2*)&e4[(size_t)ea * DOUT + lane * 2];
            float pa = fmaf(xv.x, eva.x, xv.y * eva.y);
            pa = wave_sum64(pa) * TEMPR;
            m = fmaxf(m, pa);
            if (lane == j) skeep = pa;
        }
        const float ex = (lane < deg) ? expf(skeep - m) : 0.f;
        const float Z  = wave_sum64(ex);
        if (lane < deg) Tval[csrNs[n * NC + lane]] = fmaf(EM1, vn, ex / Z);
        if (lane == 0) vArr[n] = vn;
        const float tw  = deg ? fmaf((float)deg * EM1, vn, 1.0f) : 0.f;
        const float wsn = wsArr[n];
        vxa.x = fmaf(vn,  xv.x, vxa.x); vxa.y = fmaf(vn,  xv.y, vxa.y);
        twa.x = fmaf(tw,  xv.x, twa.x); twa.y = fmaf(tw,  xv.y, twa.y);
        wsa.x = fmaf(wsn, xv.x, wsa.x); wsa.y = fmaf(wsn, xv.y, wsa.y);
    }
    if (t < DOUT) { sVX[t] = 0.f; sTX[t] = 0.f; sWX[t] = 0.f; }
    __syncthreads();
    atomicAdd(&sVX[lane*2+0], vxa.x); atomicAdd(&sVX[lane*2+1], vxa.y);
    atomicAdd(&sTX[lane*2+0], twa.x); atomicAdd(&sTX[lane*2+1], twa.y);
    atomicAdd(&sWX[lane*2+0], wsa.x); atomicAdd(&sWX[lane*2+1], wsa.y);
    __syncthreads();
    if (t < DOUT) {
        atomicAdd(&vxg[t],  sVX[t]);
        atomicAdd(&twxg[t], sTX[t]);
        atomicAdd(&wsxg[t], sWX[t]);
    }
}

__global__ __launch_bounds__(256) void k_g2(
    const int* __restrict__ degE, const int* __restrict__ csrEn,
    const float* __restrict__ Tval, const float* __restrict__ vxg,
    const float* __restrict__ x4, float* __restrict__ G2)
{
    const int t    = threadIdx.x;
    const int w    = t >> 6;
    const int lane = t & 63;
    const int e    = blockIdx.x * 4 + w;
    const int deg  = min(degE[e], EC);
    float2 acc = *(const float2*)&vxg[lane * 2];
    int j = 0;
    for (; j + 4 <= deg; j += 4) {
        const int a0 = csrEn[e*EC+j+0], a1 = csrEn[e*EC+j+1];
        const int a2 = csrEn[e*EC+j+2], a3 = csrEn[e*EC+j+3];
        const float b0 = Tval[e*EC+j+0], b1 = Tval[e*EC+j+1];
        const float b2 = Tval[e*EC+j+2], b3 = Tval[e*EC+j+3];
        const float2 f0 = *(const float2*)&x4[(size_t)a0 * DOUT + lane * 2];
        const float2 f1 = *(const float2*)&x4[(size_t)a1 * DOUT + lane * 2];
        const float2 f2 = *(const float2*)&x4[(size_t)a2 * DOUT + lane * 2];
        const float2 f3 = *(const float2*)&x4[(size_t)a3 * DOUT + lane * 2];
        acc.x = fmaf(b0, f0.x, acc.x); acc.y = fmaf(b0, f0.y, acc.y);
        acc.x = fmaf(b1, f1.x, acc.x); acc.y = fmaf(b1, f1.y, acc.y);
        acc.x = fmaf(b2, f2.x, acc.x); acc.y = fmaf(b2, f2.y, acc.y);
        acc.x = fmaf(b3, f3.x, acc.x); acc.y = fmaf(b3, f3.y, acc.y);
    }
    for (; j < deg; ++j) {
        const int   a = csrEn[e*EC+j];
        const float b = Tval[e*EC+j];
        const float2 fv = *(const float2*)&x4[(size_t)a * DOUT + lane * 2];
        acc.x = fmaf(b, fv.x, acc.x); acc.y = fmaf(b, fv.y, acc.y);
    }
    *(float2*)&G2[(size_t)e * DOUT + lane * 2] = acc;
}

__global__ __launch_bounds__(256) void k_final(
    const int* __restrict__ degN, const int* __restrict__ csrNe,
    const int* __restrict__ csrNs, const float* __restrict__ Sval,
    const float* __restrict__ Tval, const float* __restrict__ vArr,
    const float* __restrict__ c2g, const float* __restrict__ csx4,
    const float* __restrict__ wsxg, const float* __restrict__ vxg,
    const float* __restrict__ twxg,
    const float* __restrict__ G1, const float* __restrict__ G2,
    float* __restrict__ out)
{
    const int t    = threadIdx.x;
    const int w    = t >> 6;
    const int lane = t & 63;
    const int n    = blockIdx.x * 4 + w;
    const int deg  = min(degN[n], NC);
    const float vn = vArr[n];
    const float c2 = *c2g;
    const float2 c4v = *(const float2*)&csx4[lane * 2];
    const float2 wsv = *(const float2*)&wsxg[lane * 2];
    const float2 vxv = *(const float2*)&vxg[lane * 2];
    const float2 twv = *(const float2*)&twxg[lane * 2];
    float2 acc;
    acc.x = fmaf(c2, c4v.x, wsv.x) + vn * fmaf((float)Ee, vxv.x, twv.x);
    acc.y = fmaf(c2, c4v.y, wsv.y) + vn * fmaf((float)Ee, vxv.y, twv.y);
    int j = 0;
    for (; j + 2 <= deg; j += 2) {
        const int ea = csrNe[n*NC+j],   eb = csrNe[n*NC+j+1];
        const int sa = csrNs[n*NC+j],   sb = csrNs[n*NC+j+1];
        const float sva = Sval[sa], tva = Tval[sa];
        const float svb = Sval[sb], tvb = Tval[sb];
        const float2 g1a = *(const float2*)&G1[(size_t)ea * DOUT + lane * 2];
        const float2 g2a = *(const float2*)&G2[(size_t)ea * DOUT + lane * 2];
        const float2 g1b = *(const float2*)&G1[(size_t)eb * DOUT + lane * 2];
        const float2 g2b = *(const float2*)&G2[(size_t)eb * DOUT + lane * 2];
        acc.x = fmaf(sva, g1a.x, acc.x); acc.y = fmaf(sva, g1a.y, acc.y);
        acc.x = fmaf(tva, g2a.x, acc.x); acc.y = fmaf(tva, g2a.y, acc.y);
        acc.x = fmaf(svb, g1b.x, acc.x); acc.y = fmaf(svb, g1b.y, acc.y);
        acc.x = fmaf(tvb, g2b.x, acc.x); acc.y = fmaf(tvb, g2b.y, acc.y);
    }
    for (; j < deg; ++j) {
        const int ea = csrNe[n*NC+j];
        const int sa = csrNs[n*NC+j];
        const float sva = Sval[sa], tva = Tval[sa];
        const float2 g1a = *(const float2*)&G1[(size_t)ea * DOUT + lane * 2];
        const float2 g2a = *(const float2*)&G2[(size_t)ea * DOUT + lane * 2];
        acc.x = fmaf(sva, g1a.x, acc.x); acc.y = fmaf(sva, g1a.y, acc.y);
        acc.x = fmaf(tva, g2a.x, acc.x); acc.y = fmaf(tva, g2a.y, acc.y);
    }
    acc.x = acc.x > 0.f ? acc.x : expm1f(acc.x);
    acc.y = acc.y > 0.f ? acc.y : expm1f(acc.y);
    *(float2*)&out[(size_t)n * DOUT + lane * 2] = acc;
}

// ---------------------------------------------------------------------------
extern "C" void kernel_launch(void* const* d_in, const int* in_sizes, int n_in,
                              void* d_out, int out_size, void* d_ws, size_t ws_size,
                              hipStream_t stream)
{
    Prm prm;
    prm.x    = (const float*)d_in[0];
    prm.W    = (const float*)d_in[1];
    prm.W2   = (const float*)d_in[2];
    prm.W3   = (const float*)d_in[3];
    prm.bias = (const float*)d_in[4];
    prm.q    = (const float*)d_in[5];
    prm.hidx = (const int*)d_in[6];
    prm.out  = (float*)d_out;

    char* wsp = (char*)d_ws;
    size_t o = 0;
    auto take = [&](size_t bytes) {
        size_t r = o; o += (bytes + 255) & ~(size_t)255; return r;
    };
    prm.bitmap = (unsigned*)(wsp + take((size_t)Nn * Ee / 8));   // 4 MB
    prm.degE   = (int*)  (wsp + take((size_t)Ee * 4));
    prm.degN   = (int*)  (wsp + take((size_t)Nn * 4));
    prm.wsArr  = (float*)(wsp + take((size_t)Nn * 4));
    prm.c2g    = (float*)(wsp + take(4));
    prm.csx4   = (float*)(wsp + take(DOUT * 4));
    prm.csxt   = (float*)(wsp + take(DOUT * 4));
    prm.vxg    = (float*)(wsp + take(DOUT * 4));
    prm.twxg   = (float*)(wsp + take(DOUT * 4));
    prm.wsxg   = (float*)(wsp + take(DOUT * 4));
    prm.zbase  = d_ws;
    const size_t zbytes = o;
    prm.zTotal16 = (unsigned)(zbytes / 16);
    prm.x4    = (float*)(wsp + take((size_t)Nn * DOUT * 4));
    prm.xt    = (float*)(wsp + take((size_t)Nn * DOUT * 4));
    prm.rowv  = (float*)(wsp + take((size_t)Nn * 4));
    prm.vArr  = (float*)(wsp + take((size_t)Nn * 4));
    prm.csrEn = (int*)  (wsp + take((size_t)Ee * EC * 4));
    prm.Sval  = (float*)(wsp + take((size_t)Ee * EC * 4));
    prm.Tval  = (float*)(wsp + take((size_t)Ee * EC * 4));
    prm.csrNe = (int*)  (wsp + take((size_t)Nn * NC * 4));
    prm.csrNs = (int*)  (wsp + take((size_t)Nn * NC * 4));
    prm.edgeF = (float*)(wsp + take((size_t)Ee * DOUT * 4));
    prm.G1    = (float*)(wsp + take((size_t)Ee * DOUT * 4));
    prm.e4    = (float*)(wsp + take((size_t)Ee * DOUT * 4));
    prm.G2    = (float*)(wsp + take((size_t)Ee * DOUT * 4));
    (void)ws_size; (void)in_sizes; (void)n_in; (void)out_size;

    void* args[] = { &prm };
    hipError_t err = hipLaunchCooperativeKernel((void*)mega, dim3(NBLK), dim3(BLK),
                                                args, 0, stream);
    if (err != hipSuccess) {
        // Fallback: proven 7-kernel pipeline (Round 2).
        hipMemsetAsync(d_ws, 0, zbytes, stream);
        k_build <<<NNZ / 256, 256, 0, stream>>>(prm.hidx, prm.bitmap, prm.degE, prm.degN,
                                                prm.csrEn, prm.csrNe, prm.csrNs);
        k_gemm1f<<<Nn / 32,   256, 0, stream>>>(prm.x, prm.W, prm.W2, prm.bias, prm.q,
                                                prm.x4, prm.xt, prm.rowv, prm.csx4, prm.csxt);
        k_edge1 <<<Ee / 4,    256, 0, stream>>>(prm.degE, prm.csrEn, prm.rowv, prm.csx4,
                                                prm.csxt, prm.x4, prm.xt, prm.Sval,
                                                prm.edgeF, prm.G1, prm.wsArr, prm.c2g);
        k_gemm3 <<<Ee / 32,   256, 0, stream>>>(prm.edgeF, prm.W3, prm.e4);
        k_node2 <<<Nn / 16,   256, 0, stream>>>(prm.degN, prm.csrNe, prm.csrNs, prm.x4,
                                                prm.e4, prm.wsArr, prm.Tval, prm.vArr,
                                                prm.vxg, prm.twxg, prm.wsxg);
        k_g2    <<<Ee / 4,    256, 0, stream>>>(prm.degE, prm.csrEn, prm.Tval, prm.vxg,
                                                prm.x4, prm.G2);
        k_final <<<Nn / 4,    256, 0, stream>>>(prm.degN, prm.csrNe, prm.csrNs, prm.Sval,
                                                prm.Tval, prm.vArr, prm.c2g, prm.csx4,
                                                prm.wsxg, prm.vxg, prm.twxg,
                                                prm.G1, prm.G2, prm.out);
    }
}

// Round 5
// 206.694 us; speedup vs baseline: 2.0774x; 2.0774x over previous
//
#include <hip/hip_runtime.h>
#include <math.h>

// Problem constants (match reference)
constexpr int Nn   = 8192;
constexpr int Ee   = 4096;
constexpr int DIN  = 256;
constexpr int DOUT = 128;
constexpr int NNZ  = 65536;
constexpr int EC   = 96;   // capacity: nodes per edge (deg ~ Poisson(16))
constexpr int NC   = 48;   // capacity: edges per node (deg ~ Poisson(8))

#define TEMPR 0.08838834764831845f   // 1/sqrt(128)
#define EM1   1.7182818284590452f    // e - 1

static __device__ __forceinline__ float wave_sum64(float v) {
#pragma unroll
    for (int m = 32; m; m >>= 1) v += __shfl_xor(v, m, 64);
    return v;
}
static __device__ __forceinline__ float wave_max64(float v) {
#pragma unroll
    for (int m = 32; m; m >>= 1) v = fmaxf(v, __shfl_xor(v, m, 64));
    return v;
}

// ---------------------------------------------------------------------------
// K1: fused  build-CSR  +  GEMM (x4 = x@W2, xt = x@W + bias)  + epilogues
//     grid 512 x 256: first 65536 threads also process one nnz pair each.
//     16-row tiles -> 2 blocks/CU.
// ---------------------------------------------------------------------------
__global__ __launch_bounds__(256) void k_gemm1f(
    const float* __restrict__ x, const float* __restrict__ W,
    const float* __restrict__ W2, const float* __restrict__ bias,
    const float* __restrict__ q, const int* __restrict__ hidx,
    unsigned* __restrict__ bitmap, int* __restrict__ degE, int* __restrict__ degN,
    int* __restrict__ csrEn, int* __restrict__ csrNe, int* __restrict__ csrNs,
    float* __restrict__ x4, float* __restrict__ xt,
    float* __restrict__ rowv, float* __restrict__ csx4, float* __restrict__ csxt)
{
    __shared__ float sxT[32][17];
    __shared__ float swA[32][128];
    __shared__ float swB[32][128];
    __shared__ float s4[DOUT], st[DOUT];
    const int t  = threadIdx.x;
    const int tx = t & 31;
    const int ty = t >> 5;              // 0..7, owns rows ty*2, ty*2+1
    const int r0 = blockIdx.x * 16;

    // ---- CSR build (dedup via bitmap ownership) ----
    const unsigned gid = blockIdx.x * 256 + t;
    if (gid < NNZ) {
        const int n = hidx[gid];
        const int e = hidx[NNZ + gid];
        const unsigned word = (unsigned)n * (unsigned)Ee + (unsigned)e;
        const unsigned bit  = 1u << (word & 31u);
        const unsigned old  = atomicOr(&bitmap[word >> 5], bit);
        if (!(old & bit)) {
            const int pe = atomicAdd(&degE[e], 1);
            if (pe < EC) {
                csrEn[e * EC + pe] = n;
                const int pn = atomicAdd(&degN[n], 1);
                if (pn < NC) {
                    csrNe[n * NC + pn] = e;
                    csrNs[n * NC + pn] = e * EC + pe;
                }
            }
        }
    }

    // ---- GEMM ----
    float4 accA0 = {0,0,0,0}, accA1 = {0,0,0,0};
    float4 accB0 = {0,0,0,0}, accB1 = {0,0,0,0};
    for (int k0 = 0; k0 < DIN; k0 += 32) {
        __syncthreads();
        if (t < 128) {                  // stage x tile 16 rows x 32 k, transposed
            const int row = t >> 3;
            const int kq  = (t & 7) * 4;
            const float4 v = *(const float4*)&x[(size_t)(r0 + row) * DIN + k0 + kq];
            sxT[kq + 0][row] = v.x; sxT[kq + 1][row] = v.y;
            sxT[kq + 2][row] = v.z; sxT[kq + 3][row] = v.w;
        }
#pragma unroll
        for (int i = 0; i < 4; ++i) {   // stage W / W2 chunks (32 x 128)
            const int idx = t + i * 256;
            const int kr  = idx >> 5;
            const int c4  = (idx & 31) * 4;
            *(float4*)&swA[kr][c4] = *(const float4*)&W [(size_t)(k0 + kr) * DOUT + c4];
            *(float4*)&swB[kr][c4] = *(const float4*)&W2[(size_t)(k0 + kr) * DOUT + c4];
        }
        __syncthreads();
#pragma unroll
        for (int kk = 0; kk < 32; ++kk) {
            const float a0 = sxT[kk][ty * 2 + 0];
            const float a1 = sxT[kk][ty * 2 + 1];
            const float4 bA = *(const float4*)&swA[kk][tx * 4];
            const float4 bB = *(const float4*)&swB[kk][tx * 4];
            accA0.x = fmaf(a0, bA.x, accA0.x); accA0.y = fmaf(a0, bA.y, accA0.y);
            accA0.z = fmaf(a0, bA.z, accA0.z); accA0.w = fmaf(a0, bA.w, accA0.w);
            accA1.x = fmaf(a1, bA.x, accA1.x); accA1.y = fmaf(a1, bA.y, accA1.y);
            accA1.z = fmaf(a1, bA.z, accA1.z); accA1.w = fmaf(a1, bA.w, accA1.w);
            accB0.x = fmaf(a0, bB.x, accB0.x); accB0.y = fmaf(a0, bB.y, accB0.y);
            accB0.z = fmaf(a0, bB.z, accB0.z); accB0.w = fmaf(a0, bB.w, accB0.w);
            accB1.x = fmaf(a1, bB.x, accB1.x); accB1.y = fmaf(a1, bB.y, accB1.y);
            accB1.z = fmaf(a1, bB.z, accB1.z); accB1.w = fmaf(a1, bB.w, accB1.w);
        }
    }
    const float4 b4 = *(const float4*)&bias[tx * 4];
    const float4 q4 = *(const float4*)&q[tx * 4];
    const int row0 = r0 + ty * 2;
    *(float4*)&x4[(size_t)(row0 + 0) * DOUT + tx * 4] = accB0;
    *(float4*)&x4[(size_t)(row0 + 1) * DOUT + tx * 4] = accB1;
    float4 o;
    o.x = accA0.x + b4.x; o.y = accA0.y + b4.y; o.z = accA0.z + b4.z; o.w = accA0.w + b4.w;
    *(float4*)&xt[(size_t)(row0 + 0) * DOUT + tx * 4] = o;
    o.x = accA1.x + b4.x; o.y = accA1.y + b4.y; o.z = accA1.z + b4.z; o.w = accA1.w + b4.w;
    *(float4*)&xt[(size_t)(row0 + 1) * DOUT + tx * 4] = o;
    // rowv epilogue (reduce over tx; xor masks 1..16 stay within ty half)
    float pr0 = accB0.x*q4.x + accB0.y*q4.y + accB0.z*q4.z + accB0.w*q4.w;
    float pr1 = accB1.x*q4.x + accB1.y*q4.y + accB1.z*q4.z + accB1.w*q4.w;
#pragma unroll
    for (int m = 16; m; m >>= 1) {
        pr0 += __shfl_xor(pr0, m, 64);
        pr1 += __shfl_xor(pr1, m, 64);
    }
    if (tx == 0) {
        rowv[row0 + 0] = pr0 * TEMPR;
        rowv[row0 + 1] = pr1 * TEMPR;
    }
    // column-sum epilogue
    if (t < DOUT) { s4[t] = 0.f; st[t] = 0.f; }
    __syncthreads();
    const float b4v[4] = {b4.x, b4.y, b4.z, b4.w};
    const float sB[4] = {accB0.x + accB1.x, accB0.y + accB1.y,
                         accB0.z + accB1.z, accB0.w + accB1.w};
    const float sA[4] = {accA0.x + accA1.x + 2.f*b4v[0], accA0.y + accA1.y + 2.f*b4v[1],
                         accA0.z + accA1.z + 2.f*b4v[2], accA0.w + accA1.w + 2.f*b4v[3]};
#pragma unroll
    for (int c = 0; c < 4; ++c) {
        atomicAdd(&s4[tx * 4 + c], sB[c]);
        atomicAdd(&st[tx * 4 + c], sA[c]);
    }
    __syncthreads();
    if (t < DOUT) { atomicAdd(&csx4[t], s4[t]); atomicAdd(&csxt[t], st[t]); }
}

// ---------------------------------------------------------------------------
// K2: per-edge (1 wave/edge, 1024 blocks): softmax1 -> Sval + ws scatter + c2,
//     then gather  edgeF = att1 @ xt,  G1 = att1 @ x4   (unroll-8)
// ---------------------------------------------------------------------------
__global__ __launch_bounds__(256) void k_edge1(
    const int* __restrict__ degE, const int* __restrict__ csrEn,
    const float* __restrict__ rowv,
    const float* __restrict__ csx4, const float* __restrict__ csxt,
    const float* __restrict__ x4, const float* __restrict__ xt,
    float* __restrict__ Sval, float* __restrict__ edgeF, float* __restrict__ G1,
    float* __restrict__ wsArr, float* __restrict__ c2g)
{
    __shared__ int   sN[4][EC];
    __shared__ float sS[4][EC];
    __shared__ float sC2[4];
    const int t    = threadIdx.x;
    const int w    = t >> 6;
    const int lane = t & 63;
    const int e    = blockIdx.x * 4 + w;
    const int deg  = min(degE[e], EC);
    const float ue = deg ? 1.0f / ((float)Nn + (float)deg * EM1) : 2.0f / (float)Nn;

    int   n0 = 0, n1 = 0;
    float r0 = -INFINITY, r1 = -INFINITY;
    if (lane < deg)      { n0 = csrEn[e * EC + lane];      r0 = rowv[n0]; }
    if (lane + 64 < deg) { n1 = csrEn[e * EC + lane + 64]; r1 = rowv[n1]; }
    const float m  = wave_max64(fmaxf(r0, r1));
    const float e0 = (lane < deg)      ? expf(r0 - m) : 0.f;
    const float e1 = (lane + 64 < deg) ? expf(r1 - m) : 0.f;
    const float Z  = wave_sum64(e0 + e1);
    const float inv = deg ? 1.0f / Z : 0.f;
    const float base = EM1 * ue;
    if (lane < deg) {
        const float sv = fmaf(e0, inv, base);
        sN[w][lane] = n0; sS[w][lane] = sv;
        Sval[e * EC + lane] = sv;
        atomicAdd(&wsArr[n0], ue * sv);
    }
    if (lane + 64 < deg) {
        const float sv = fmaf(e1, inv, base);
        sN[w][lane + 64] = n1; sS[w][lane + 64] = sv;
        Sval[e * EC + lane + 64] = sv;
        atomicAdd(&wsArr[n1], ue * sv);
    }

    const float2 ct = *(const float2*)&csxt[lane * 2];
    const float2 c4 = *(const float2*)&csx4[lane * 2];
    float2 aE = make_float2(ue * ct.x, ue * ct.y);
    float2 aG = make_float2(ue * c4.x, ue * c4.y);
    int j = 0;
    for (; j + 8 <= deg; j += 8) {
        int   ai[8]; float bi[8]; float2 tv[8], fv[8];
#pragma unroll
        for (int k = 0; k < 8; ++k) { ai[k] = sN[w][j+k]; bi[k] = sS[w][j+k]; }
#pragma unroll
        for (int k = 0; k < 8; ++k) {
            tv[k] = *(const float2*)&xt[(size_t)ai[k] * DOUT + lane * 2];
            fv[k] = *(const float2*)&x4[(size_t)ai[k] * DOUT + lane * 2];
        }
#pragma unroll
        for (int k = 0; k < 8; ++k) {
            aE.x = fmaf(bi[k], tv[k].x, aE.x); aE.y = fmaf(bi[k], tv[k].y, aE.y);
            aG.x = fmaf(bi[k], fv[k].x, aG.x); aG.y = fmaf(bi[k], fv[k].y, aG.y);
        }
    }
    for (; j < deg; ++j) {
        const int   a = sN[w][j];
        const float b = sS[w][j];
        const float2 tv = *(const float2*)&xt[(size_t)a * DOUT + lane * 2];
        const float2 fv = *(const float2*)&x4[(size_t)a * DOUT + lane * 2];
        aE.x = fmaf(b, tv.x, aE.x); aE.y = fmaf(b, tv.y, aE.y);
        aG.x = fmaf(b, fv.x, aG.x); aG.y = fmaf(b, fv.y, aG.y);
    }
    *(float2*)&edgeF[(size_t)e * DOUT + lane * 2] = aE;
    *(float2*)&G1  [(size_t)e * DOUT + lane * 2] = aG;

    if (lane == 0) sC2[w] = ue * ue;
    __syncthreads();
    if (t == 0) atomicAdd(c2g, sC2[0] + sC2[1] + sC2[2] + sC2[3]);
}

// ---------------------------------------------------------------------------
// K3: edge4 = edgeF @ W3   (16-row tiles, 256 blocks)
// ---------------------------------------------------------------------------
__global__ __launch_bounds__(256) void k_gemm3(
    const float* __restrict__ A, const float* __restrict__ W3,
    float* __restrict__ C)
{
    __shared__ float sxT[32][17];
    __shared__ float sw[32][128];
    const int t  = threadIdx.x;
    const int tx = t & 31;
    const int ty = t >> 5;
    const int r0 = blockIdx.x * 16;
    float4 acc0 = {0,0,0,0}, acc1 = {0,0,0,0};
    for (int k0 = 0; k0 < DOUT; k0 += 32) {
        __syncthreads();
        if (t < 128) {
            const int row = t >> 3;
            const int kq  = (t & 7) * 4;
            const float4 v = *(const float4*)&A[(size_t)(r0 + row) * DOUT + k0 + kq];
            sxT[kq + 0][row] = v.x; sxT[kq + 1][row] = v.y;
            sxT[kq + 2][row] = v.z; sxT[kq + 3][row] = v.w;
        }
#pragma unroll
        for (int i = 0; i < 4; ++i) {
            const int idx = t + i * 256;
            const int kr  = idx >> 5;
            const int c4  = (idx & 31) * 4;
            *(float4*)&sw[kr][c4] = *(const float4*)&W3[(size_t)(k0 + kr) * DOUT + c4];
        }
        __syncthreads();
#pragma unroll
        for (int kk = 0; kk < 32; ++kk) {
            const float a0 = sxT[kk][ty * 2 + 0];
            const float a1 = sxT[kk][ty * 2 + 1];
            const float4 b = *(const float4*)&sw[kk][tx * 4];
            acc0.x = fmaf(a0, b.x, acc0.x); acc0.y = fmaf(a0, b.y, acc0.y);
            acc0.z = fmaf(a0, b.z, acc0.z); acc0.w = fmaf(a0, b.w, acc0.w);
            acc1.x = fmaf(a1, b.x, acc1.x); acc1.y = fmaf(a1, b.y, acc1.y);
            acc1.z = fmaf(a1, b.z, acc1.z); acc1.w = fmaf(a1, b.w, acc1.w);
        }
    }
    const int row0 = r0 + ty * 2;
    *(float4*)&C[(size_t)(row0 + 0) * DOUT + tx * 4] = acc0;
    *(float4*)&C[(size_t)(row0 + 1) * DOUT + tx * 4] = acc1;
}

// ---------------------------------------------------------------------------
// K4: per-node softmax2, LANE-PER-EDGE streaming:
//     lane j computes dot(x4[n], e4[e_j]) by streaming e4 row (32 float4,
//     unroll-8) against x4[n] staged in LDS (broadcast reads).
//     2 nodes per wave serially; epilogue weighted colsums.
// ---------------------------------------------------------------------------
__global__ __launch_bounds__(256) void k_node2(
    const int* __restrict__ degN, const int* __restrict__ csrNe,
    const int* __restrict__ csrNs, const float* __restrict__ x4,
    const float* __restrict__ e4, const float* __restrict__ wsArr,
    float* __restrict__ Tval, float* __restrict__ vArr,
    float* __restrict__ vxg, float* __restrict__ twxg, float* __restrict__ wsxg)
{
    __shared__ float sx[4][DOUT];
    __shared__ float sVX[DOUT], sTX[DOUT], sWX[DOUT];
    const int t    = threadIdx.x;
    const int w    = t >> 6;
    const int lane = t & 63;

    float2 vxa = {0,0}, twa = {0,0}, wsa = {0,0};
#pragma unroll
    for (int s = 0; s < 2; ++s) {
        const int n   = blockIdx.x * 8 + w * 2 + s;
        const int deg = min(degN[n], NC);
        const float vn = deg ? 1.0f / ((float)Ee + (float)deg * EM1) : 2.0f / (float)Ee;
        // stage x4[n] into this wave's LDS row
        const float2 xv = *(const float2*)&x4[(size_t)n * DOUT + lane * 2];
        __syncthreads();
        sx[w][lane * 2 + 0] = xv.x;
        sx[w][lane * 2 + 1] = xv.y;
        __syncthreads();
        // lane j: streaming dot with e4[e_j]
        int ej = 0, slot = 0;
        if (lane < deg) { ej = csrNe[n * NC + lane]; slot = csrNs[n * NC + lane]; }
        const float4* er = (const float4*)&e4[(size_t)ej * DOUT];
        float dot = 0.f;
#pragma unroll
        for (int c0 = 0; c0 < 32; c0 += 8) {
            float4 ev[8];
#pragma unroll
            for (int k = 0; k < 8; ++k) ev[k] = er[c0 + k];
#pragma unroll
            for (int k = 0; k < 8; ++k) {
                const float4 xc = *(const float4*)&sx[w][(c0 + k) * 4];
                dot = fmaf(ev[k].x, xc.x, dot); dot = fmaf(ev[k].y, xc.y, dot);
                dot = fmaf(ev[k].z, xc.z, dot); dot = fmaf(ev[k].w, xc.w, dot);
            }
        }
        const float sj = (lane < deg) ? dot * TEMPR : -INFINITY;
        const float m  = wave_max64(sj);
        const float ex = (lane < deg) ? expf(sj - m) : 0.f;
        const float Z  = wave_sum64(ex);
        if (lane < deg) Tval[slot] = fmaf(EM1, vn, ex / Z);
        if (lane == 0) vArr[n] = vn;
        const float tw  = deg ? fmaf((float)deg * EM1, vn, 1.0f) : 0.f;
        const float wsn = wsArr[n];
        vxa.x = fmaf(vn,  xv.x, vxa.x); vxa.y = fmaf(vn,  xv.y, vxa.y);
        twa.x = fmaf(tw,  xv.x, twa.x); twa.y = fmaf(tw,  xv.y, twa.y);
        wsa.x = fmaf(wsn, xv.x, wsa.x); wsa.y = fmaf(wsn, xv.y, wsa.y);
    }
    __syncthreads();
    if (t < DOUT) { sVX[t] = 0.f; sTX[t] = 0.f; sWX[t] = 0.f; }
    __syncthreads();
    atomicAdd(&sVX[lane*2+0], vxa.x); atomicAdd(&sVX[lane*2+1], vxa.y);
    atomicAdd(&sTX[lane*2+0], twa.x); atomicAdd(&sTX[lane*2+1], twa.y);
    atomicAdd(&sWX[lane*2+0], wsa.x); atomicAdd(&sWX[lane*2+1], wsa.y);
    __syncthreads();
    if (t < DOUT) {
        atomicAdd(&vxg[t],  sVX[t]);
        atomicAdd(&twxg[t], sTX[t]);
        atomicAdd(&wsxg[t], sWX[t]);
    }
}

// ---------------------------------------------------------------------------
// K5: per-edge: G2[e] = vx + sum_{n in e} T[e,n] * x4[n]   (unroll-8)
// ---------------------------------------------------------------------------
__global__ __launch_bounds__(256) void k_g2(
    const int* __restrict__ degE, const int* __restrict__ csrEn,
    const float* __restrict__ Tval, const float* __restrict__ vxg,
    const float* __restrict__ x4, float* __restrict__ G2)
{
    const int t    = threadIdx.x;
    const int w    = t >> 6;
    const int lane = t & 63;
    const int e    = blockIdx.x * 4 + w;
    const int deg  = min(degE[e], EC);
    float2 acc = *(const float2*)&vxg[lane * 2];
    int j = 0;
    for (; j + 8 <= deg; j += 8) {
        int ai[8]; float bi[8]; float2 fv[8];
#pragma unroll
        for (int k = 0; k < 8; ++k) { ai[k] = csrEn[e*EC+j+k]; bi[k] = Tval[e*EC+j+k]; }
#pragma unroll
        for (int k = 0; k < 8; ++k)
            fv[k] = *(const float2*)&x4[(size_t)ai[k] * DOUT + lane * 2];
#pragma unroll
        for (int k = 0; k < 8; ++k) {
            acc.x = fmaf(bi[k], fv[k].x, acc.x); acc.y = fmaf(bi[k], fv[k].y, acc.y);
        }
    }
    for (; j < deg; ++j) {
        const int   a = csrEn[e*EC+j];
        const float b = Tval[e*EC+j];
        const float2 fv = *(const float2*)&x4[(size_t)a * DOUT + lane * 2];
        acc.x = fmaf(b, fv.x, acc.x); acc.y = fmaf(b, fv.y, acc.y);
    }
    *(float2*)&G2[(size_t)e * DOUT + lane * 2] = acc;
}

// ---------------------------------------------------------------------------
// K6: final per-node combine + elu  (1 node/wave, 2048 blocks, unroll-4)
// ---------------------------------------------------------------------------
__global__ __launch_bounds__(256) void k_final(
    const int* __restrict__ degN, const int* __restrict__ csrNe,
    const int* __restrict__ csrNs, const float* __restrict__ Sval,
    const float* __restrict__ Tval, const float* __restrict__ vArr,
    const float* __restrict__ c2g, const float* __restrict__ csx4,
    const float* __restrict__ wsxg, const float* __restrict__ vxg,
    const float* __restrict__ twxg,
    const float* __restrict__ G1, const float* __restrict__ G2,
    float* __restrict__ out)
{
    const int t    = threadIdx.x;
    const int w    = t >> 6;
    const int lane = t & 63;
    const int n    = blockIdx.x * 4 + w;
    const int deg  = min(degN[n], NC);
    const float vn = vArr[n];
    const float c2 = *c2g;
    const float2 c4v = *(const float2*)&csx4[lane * 2];
    const float2 wsv = *(const float2*)&wsxg[lane * 2];
    const float2 vxv = *(const float2*)&vxg[lane * 2];
    const float2 twv = *(const float2*)&twxg[lane * 2];
    float2 acc;
    acc.x = fmaf(c2, c4v.x, wsv.x) + vn * fmaf((float)Ee, vxv.x, twv.x);
    acc.y = fmaf(c2, c4v.y, wsv.y) + vn * fmaf((float)Ee, vxv.y, twv.y);
    int j = 0;
    for (; j + 4 <= deg; j += 4) {
        int ei[4], si[4]; float sv[4], tv[4]; float2 g1[4], g2[4];
#pragma unroll
        for (int k = 0; k < 4; ++k) {
            ei[k] = csrNe[n*NC+j+k]; si[k] = csrNs[n*NC+j+k];
        }
#pragma unroll
        for (int k = 0; k < 4; ++k) {
            sv[k] = Sval[si[k]]; tv[k] = Tval[si[k]];
            g1[k] = *(const float2*)&G1[(size_t)ei[k] * DOUT + lane * 2];
            g2[k] = *(const float2*)&G2[(size_t)ei[k] * DOUT + lane * 2];
        }
#pragma unroll
        for (int k = 0; k < 4; ++k) {
            acc.x = fmaf(sv[k], g1[k].x, acc.x); acc.y = fmaf(sv[k], g1[k].y, acc.y);
            acc.x = fmaf(tv[k], g2[k].x, acc.x); acc.y = fmaf(tv[k], g2[k].y, acc.y);
        }
    }
    for (; j < deg; ++j) {
        const int ea = csrNe[n*NC+j];
        const int sa = csrNs[n*NC+j];
        const float sva = Sval[sa], tva = Tval[sa];
        const float2 g1a = *(const float2*)&G1[(size_t)ea * DOUT + lane * 2];
        const float2 g2a = *(const float2*)&G2[(size_t)ea * DOUT + lane * 2];
        acc.x = fmaf(sva, g1a.x, acc.x); acc.y = fmaf(sva, g1a.y, acc.y);
        acc.x = fmaf(tva, g2a.x, acc.x); acc.y = fmaf(tva, g2a.y, acc.y);
    }
    acc.x = acc.x > 0.f ? acc.x : expm1f(acc.x);
    acc.y = acc.y > 0.f ? acc.y : expm1f(acc.y);
    *(float2*)&out[(size_t)n * DOUT + lane * 2] = acc;
}

// ---------------------------------------------------------------------------
extern "C" void kernel_launch(void* const* d_in, const int* in_sizes, int n_in,
                              void* d_out, int out_size, void* d_ws, size_t ws_size,
                              hipStream_t stream)
{
    const float* x    = (const float*)d_in[0];
    const float* W    = (const float*)d_in[1];
    const float* W2   = (const float*)d_in[2];
    const float* W3   = (const float*)d_in[3];
    const float* bias = (const float*)d_in[4];
    const float* q    = (const float*)d_in[5];
    const int*   hidx = (const int*)d_in[6];
    float* out = (float*)d_out;

    char* wsp = (char*)d_ws;
    size_t o = 0;
    auto take = [&](size_t bytes) {
        size_t r = o; o += (bytes + 255) & ~(size_t)255; return r;
    };
    // --- zero-initialized region (one memset) ---
    unsigned* bitmap = (unsigned*)(wsp + take((size_t)Nn * Ee / 8));   // 4 MB
    int*   degE  = (int*)  (wsp + take((size_t)Ee * 4));
    int*   degN  = (int*)  (wsp + take((size_t)Nn * 4));
    float* wsArr = (float*)(wsp + take((size_t)Nn * 4));
    float* c2g   = (float*)(wsp + take(4));
    float* csx4  = (float*)(wsp + take(DOUT * 4));
    float* csxt  = (float*)(wsp + take(DOUT * 4));
    float* vxg   = (float*)(wsp + take(DOUT * 4));
    float* twxg  = (float*)(wsp + take(DOUT * 4));
    float* wsxg  = (float*)(wsp + take(DOUT * 4));
    const size_t zbytes = o;
    // --- fully-overwritten scratch ---
    float* x4    = (float*)(wsp + take((size_t)Nn * DOUT * 4));
    float* xt    = (float*)(wsp + take((size_t)Nn * DOUT * 4));
    float* rowv  = (float*)(wsp + take((size_t)Nn * 4));
    float* vArr  = (float*)(wsp + take((size_t)Nn * 4));
    int*   csrEn = (int*)  (wsp + take((size_t)Ee * EC * 4));
    float* Sval  = (float*)(wsp + take((size_t)Ee * EC * 4));
    float* Tval  = (float*)(wsp + take((size_t)Ee * EC * 4));
    int*   csrNe = (int*)  (wsp + take((size_t)Nn * NC * 4));
    int*   csrNs = (int*)  (wsp + take((size_t)Nn * NC * 4));
    float* edgeF = (float*)(wsp + take((size_t)Ee * DOUT * 4));
    float* G1    = (float*)(wsp + take((size_t)Ee * DOUT * 4));
    float* e4    = (float*)(wsp + take((size_t)Ee * DOUT * 4));
    float* G2    = (float*)(wsp + take((size_t)Ee * DOUT * 4));
    (void)ws_size; (void)in_sizes; (void)n_in; (void)out_size;

    hipMemsetAsync(d_ws, 0, zbytes, stream);

    k_gemm1f<<<Nn / 16, 256, 0, stream>>>(x, W, W2, bias, q, hidx,
                                          bitmap, degE, degN, csrEn, csrNe, csrNs,
                                          x4, xt, rowv, csx4, csxt);
    k_edge1 <<<Ee / 4,  256, 0, stream>>>(degE, csrEn, rowv, csx4, csxt,
                                          x4, xt, Sval, edgeF, G1, wsArr, c2g);
    k_gemm3 <<<Ee / 16, 256, 0, stream>>>(edgeF, W3, e4);
    k_node2 <<<Nn / 8,  256, 0, stream>>>(degN, csrNe, csrNs, x4, e4, wsArr,
                                          Tval, vArr, vxg, twxg, wsxg);
    k_g2    <<<Ee / 4,  256, 0, stream>>>(degE, csrEn, Tval, vxg, x4, G2);
    k_final <<<Nn / 4,  256, 0, stream>>>(degN, csrNe, csrNs, Sval, Tval, vArr,
                                          c2g, csx4, wsxg, vxg, twxg, G1, G2, out);
}

// Round 6
// 198.875 us; speedup vs baseline: 2.1590x; 1.0393x over previous
//
#include <hip/hip_runtime.h>
#include <math.h>

// Problem constants (match reference)
constexpr int Nn   = 8192;
constexpr int Ee   = 4096;
constexpr int DIN  = 256;
constexpr int DOUT = 128;
constexpr int NNZ  = 65536;
constexpr int EC   = 96;   // capacity: nodes per edge (deg ~ Poisson(16))
constexpr int NC   = 48;   // capacity: edges per node (deg ~ Poisson(8))

#define TEMPR 0.08838834764831845f   // 1/sqrt(128)
#define EM1   1.7182818284590452f    // e - 1

typedef __attribute__((ext_vector_type(8))) short short8;
typedef __attribute__((ext_vector_type(4))) float f32x4;

static __device__ __forceinline__ float wave_sum64(float v) {
#pragma unroll
    for (int m = 32; m; m >>= 1) v += __shfl_xor(v, m, 64);
    return v;
}
static __device__ __forceinline__ float wave_max64(float v) {
#pragma unroll
    for (int m = 32; m; m >>= 1) v = fmaxf(v, __shfl_xor(v, m, 64));
    return v;
}
static __device__ __forceinline__ short f2bf(float f) {
    union { float f; unsigned u; } v; v.f = f;
    const unsigned r = (v.u + 0x7FFFu + ((v.u >> 16) & 1u)) >> 16;
    return (short)r;
}

// ---------------------------------------------------------------------------
// K0: prologue.
//  blocks 0..31 : WW3 = W @ W3  (256x128), written transposed-bf16 WWT[c][r]
//  blocks 32..39: W2 transpose-bf16  W2T[n][k]  (from W2 [k][n])
//  block  40    : bW3 = bias @ W3  (fp32, 128)
// ---------------------------------------------------------------------------
__global__ __launch_bounds__(256) void k_ww3(
    const float* __restrict__ W, const float* __restrict__ W2,
    const float* __restrict__ W3, const float* __restrict__ bias,
    short* __restrict__ W2T, short* __restrict__ WWT, float* __restrict__ bW3)
{
    const int b = blockIdx.x;
    const int t = threadIdx.x;
    if (b < 32) {
        __shared__ float sW[8][128];
        const int r0 = b * 8;
        for (int i = t; i < 1024; i += 256)
            sW[i >> 7][i & 127] = W[(size_t)(r0 + (i >> 7)) * DOUT + (i & 127)];
        __syncthreads();
        const int c  = t & 127;
        const int rh = (t >> 7) * 4;
        float acc[4] = {0.f, 0.f, 0.f, 0.f};
        for (int k = 0; k < 128; ++k) {
            const float w3 = W3[(size_t)k * DOUT + c];
#pragma unroll
            for (int i = 0; i < 4; ++i) acc[i] = fmaf(sW[rh + i][k], w3, acc[i]);
        }
#pragma unroll
        for (int i = 0; i < 4; ++i)
            WWT[(size_t)c * DIN + (r0 + rh + i)] = f2bf(acc[i]);
    } else if (b < 40) {
        const int k0 = (b - 32) * 32;
        for (int i = t; i < 32 * 128; i += 256) {
            const int k = k0 + (i >> 7);
            const int n = i & 127;
            W2T[(size_t)n * DIN + k] = f2bf(W2[(size_t)k * DOUT + n]);
        }
    } else {
        if (t < 128) {
            float acc = 0.f;
            for (int k = 0; k < 128; ++k)
                acc = fmaf(bias[k], W3[(size_t)k * DOUT + t], acc);
            bW3[t] = acc;
        }
    }
}

// ---------------------------------------------------------------------------
// K1: MFMA GEMM  x4 = x @ W2,  xw = x @ WW3 + bW3   + CSR build + epilogues
//  16-row tile / block, 4 waves each owning 32 cols (2 n-tiles).
//  No LDS in main loop: A from x (fp32->bf16 in-reg), B from pre-transposed
//  bf16 weights. Epilogues: rowv (q . x4-row), colsums csx4/csxw.
// ---------------------------------------------------------------------------
__global__ __launch_bounds__(256) void k_gemm1f(
    const float* __restrict__ x, const short* __restrict__ W2T,
    const short* __restrict__ WWT, const float* __restrict__ bW3,
    const float* __restrict__ q, const int* __restrict__ hidx,
    unsigned* __restrict__ bitmap, int* __restrict__ degE, int* __restrict__ degN,
    int* __restrict__ csrEn, int* __restrict__ csrNe, int* __restrict__ csrNs,
    float* __restrict__ x4, float* __restrict__ xw,
    float* __restrict__ rowv, float* __restrict__ csx4, float* __restrict__ csxw)
{
    __shared__ float s4[DOUT], sw[DOUT], srow[16];
    const int t    = threadIdx.x;
    const int lane = t & 63;
    const int wv   = t >> 6;
    const int n16  = lane & 15;
    const int quad = lane >> 4;
    const int r0   = blockIdx.x * 16;
    const int n0   = wv * 32;

    // ---- CSR build (dedup via bitmap ownership); grid 512*256 covers NNZ ----
    const unsigned gid = blockIdx.x * 256 + t;
    if (gid < NNZ) {
        const int n = hidx[gid];
        const int e = hidx[NNZ + gid];
        const unsigned word = (unsigned)n * (unsigned)Ee + (unsigned)e;
        const unsigned bit  = 1u << (word & 31u);
        const unsigned old  = atomicOr(&bitmap[word >> 5], bit);
        if (!(old & bit)) {
            const int pe = atomicAdd(&degE[e], 1);
            if (pe < EC) {
                csrEn[e * EC + pe] = n;
                const int pn = atomicAdd(&degN[n], 1);
                if (pn < NC) {
                    csrNe[n * NC + pn] = e;
                    csrNs[n * NC + pn] = e * EC + pe;
                }
            }
        }
    }

    // ---- MFMA main loop ----
    f32x4 acc4[2], accw[2];
#pragma unroll
    for (int nt = 0; nt < 2; ++nt) {
        acc4[nt] = (f32x4){0.f, 0.f, 0.f, 0.f};
        accw[nt] = (f32x4){0.f, 0.f, 0.f, 0.f};
    }
#pragma unroll
    for (int k0 = 0; k0 < DIN; k0 += 32) {
        const int kb = k0 + quad * 8;
        const float4 xa = *(const float4*)&x[(size_t)(r0 + n16) * DIN + kb];
        const float4 xb = *(const float4*)&x[(size_t)(r0 + n16) * DIN + kb + 4];
        short8 af;
        af[0] = f2bf(xa.x); af[1] = f2bf(xa.y); af[2] = f2bf(xa.z); af[3] = f2bf(xa.w);
        af[4] = f2bf(xb.x); af[5] = f2bf(xb.y); af[6] = f2bf(xb.z); af[7] = f2bf(xb.w);
#pragma unroll
        for (int nt = 0; nt < 2; ++nt) {
            const int col = n0 + nt * 16 + n16;
            const short8 b4 = *(const short8*)&W2T[(size_t)col * DIN + kb];
            const short8 bw = *(const short8*)&WWT[(size_t)col * DIN + kb];
            acc4[nt] = __builtin_amdgcn_mfma_f32_16x16x32_bf16(af, b4, acc4[nt], 0, 0, 0);
            accw[nt] = __builtin_amdgcn_mfma_f32_16x16x32_bf16(af, bw, accw[nt], 0, 0, 0);
        }
    }

    // ---- writeback + epilogues ----
    float bwv[2], qv[2];
#pragma unroll
    for (int nt = 0; nt < 2; ++nt) {
        const int col = n0 + nt * 16 + n16;
        bwv[nt] = bW3[col];
        qv[nt]  = q[col];
    }
#pragma unroll
    for (int nt = 0; nt < 2; ++nt) {
        const int col = n0 + nt * 16 + n16;
#pragma unroll
        for (int reg = 0; reg < 4; ++reg) {
            const int row = r0 + quad * 4 + reg;
            x4[(size_t)row * DOUT + col] = acc4[nt][reg];
            xw[(size_t)row * DOUT + col] = accw[nt][reg] + bwv[nt];
        }
    }
    // rowv partials: reduce over n within quad (masks 1..8 stay in quad)
    float pr[4];
#pragma unroll
    for (int reg = 0; reg < 4; ++reg)
        pr[reg] = qv[0] * acc4[0][reg] + qv[1] * acc4[1][reg];
#pragma unroll
    for (int m = 8; m; m >>= 1) {
#pragma unroll
        for (int reg = 0; reg < 4; ++reg) pr[reg] += __shfl_xor(pr[reg], m, 64);
    }
    if (t < 16) srow[t] = 0.f;
    if (t < DOUT) { s4[t] = 0.f; sw[t] = 0.f; }
    __syncthreads();
    if (n16 == 0) {
#pragma unroll
        for (int reg = 0; reg < 4; ++reg) atomicAdd(&srow[quad * 4 + reg], pr[reg]);
    }
#pragma unroll
    for (int nt = 0; nt < 2; ++nt) {
        const int col = n0 + nt * 16 + n16;
        const float c4s = acc4[nt][0] + acc4[nt][1] + acc4[nt][2] + acc4[nt][3];
        const float cws = accw[nt][0] + accw[nt][1] + accw[nt][2] + accw[nt][3]
                        + 4.f * bwv[nt];
        atomicAdd(&s4[col], c4s);
        atomicAdd(&sw[col], cws);
    }
    __syncthreads();
    if (t < 16) rowv[r0 + t] = srow[t] * TEMPR;
    if (t < DOUT) { atomicAdd(&csx4[t], s4[t]); atomicAdd(&csxw[t], sw[t]); }
}

// ---------------------------------------------------------------------------
// K2: per-edge (1 wave/edge): softmax1 -> Sval + ws scatter + c2, then gather
//     e4 = att1 @ xw   (direct — replaces edgeF+gemm3),  G1 = att1 @ x4.
// ---------------------------------------------------------------------------
__global__ __launch_bounds__(256) void k_edge1(
    const int* __restrict__ degE, const int* __restrict__ csrEn,
    const float* __restrict__ rowv,
    const float* __restrict__ csx4, const float* __restrict__ csxw,
    const float* __restrict__ x4, const float* __restrict__ xw,
    float* __restrict__ Sval, float* __restrict__ e4out, float* __restrict__ G1,
    float* __restrict__ wsArr, float* __restrict__ c2g)
{
    __shared__ int   sN[4][EC];
    __shared__ float sS[4][EC];
    __shared__ float sC2[4];
    const int t    = threadIdx.x;
    const int w    = t >> 6;
    const int lane = t & 63;
    const int e    = blockIdx.x * 4 + w;
    const int deg  = min(degE[e], EC);
    const float ue = deg ? 1.0f / ((float)Nn + (float)deg * EM1) : 2.0f / (float)Nn;

    int   n0 = 0, n1 = 0;
    float r0 = -INFINITY, r1 = -INFINITY;
    if (lane < deg)      { n0 = csrEn[e * EC + lane];      r0 = rowv[n0]; }
    if (lane + 64 < deg) { n1 = csrEn[e * EC + lane + 64]; r1 = rowv[n1]; }
    const float m  = wave_max64(fmaxf(r0, r1));
    const float e0 = (lane < deg)      ? expf(r0 - m) : 0.f;
    const float e1 = (lane + 64 < deg) ? expf(r1 - m) : 0.f;
    const float Z  = wave_sum64(e0 + e1);
    const float inv = deg ? 1.0f / Z : 0.f;
    const float base = EM1 * ue;
    if (lane < deg) {
        const float sv = fmaf(e0, inv, base);
        sN[w][lane] = n0; sS[w][lane] = sv;
        Sval[e * EC + lane] = sv;
        atomicAdd(&wsArr[n0], ue * sv);
    }
    if (lane + 64 < deg) {
        const float sv = fmaf(e1, inv, base);
        sN[w][lane + 64] = n1; sS[w][lane + 64] = sv;
        Sval[e * EC + lane + 64] = sv;
        atomicAdd(&wsArr[n1], ue * sv);
    }

    const float2 cw = *(const float2*)&csxw[lane * 2];
    const float2 c4 = *(const float2*)&csx4[lane * 2];
    float2 aE = make_float2(ue * cw.x, ue * cw.y);
    float2 aG = make_float2(ue * c4.x, ue * c4.y);
    int j = 0;
    for (; j + 8 <= deg; j += 8) {
        int   ai[8]; float bi[8]; float2 tv[8], fv[8];
#pragma unroll
        for (int k = 0; k < 8; ++k) { ai[k] = sN[w][j+k]; bi[k] = sS[w][j+k]; }
#pragma unroll
        for (int k = 0; k < 8; ++k) {
            tv[k] = *(const float2*)&xw[(size_t)ai[k] * DOUT + lane * 2];
            fv[k] = *(const float2*)&x4[(size_t)ai[k] * DOUT + lane * 2];
        }
#pragma unroll
        for (int k = 0; k < 8; ++k) {
            aE.x = fmaf(bi[k], tv[k].x, aE.x); aE.y = fmaf(bi[k], tv[k].y, aE.y);
            aG.x = fmaf(bi[k], fv[k].x, aG.x); aG.y = fmaf(bi[k], fv[k].y, aG.y);
        }
    }
    for (; j < deg; ++j) {
        const int   a = sN[w][j];
        const float b = sS[w][j];
        const float2 tv = *(const float2*)&xw[(size_t)a * DOUT + lane * 2];
        const float2 fv = *(const float2*)&x4[(size_t)a * DOUT + lane * 2];
        aE.x = fmaf(b, tv.x, aE.x); aE.y = fmaf(b, tv.y, aE.y);
        aG.x = fmaf(b, fv.x, aG.x); aG.y = fmaf(b, fv.y, aG.y);
    }
    *(float2*)&e4out[(size_t)e * DOUT + lane * 2] = aE;
    *(float2*)&G1   [(size_t)e * DOUT + lane * 2] = aG;

    if (lane == 0) sC2[w] = ue * ue;
    __syncthreads();
    if (t == 0) atomicAdd(c2g, sC2[0] + sC2[1] + sC2[2] + sC2[3]);
}

// ---------------------------------------------------------------------------
// K3: per-node softmax2 (lane-per-edge streaming dots) -> Tval, v[n];
//     weighted colsum epilogues.
// ---------------------------------------------------------------------------
__global__ __launch_bounds__(256) void k_node2(
    const int* __restrict__ degN, const int* __restrict__ csrNe,
    const int* __restrict__ csrNs, const float* __restrict__ x4,
    const float* __restrict__ e4, const float* __restrict__ wsArr,
    float* __restrict__ Tval, float* __restrict__ vArr,
    float* __restrict__ vxg, float* __restrict__ twxg, float* __restrict__ wsxg)
{
    __shared__ float sx[4][DOUT];
    __shared__ float sVX[DOUT], sTX[DOUT], sWX[DOUT];
    const int t    = threadIdx.x;
    const int w    = t >> 6;
    const int lane = t & 63;

    float2 vxa = {0,0}, twa = {0,0}, wsa = {0,0};
#pragma unroll
    for (int s = 0; s < 2; ++s) {
        const int n   = blockIdx.x * 8 + w * 2 + s;
        const int deg = min(degN[n], NC);
        const float vn = deg ? 1.0f / ((float)Ee + (float)deg * EM1) : 2.0f / (float)Ee;
        const float2 xv = *(const float2*)&x4[(size_t)n * DOUT + lane * 2];
        __syncthreads();
        sx[w][lane * 2 + 0] = xv.x;
        sx[w][lane * 2 + 1] = xv.y;
        __syncthreads();
        int ej = 0, slot = 0;
        if (lane < deg) { ej = csrNe[n * NC + lane]; slot = csrNs[n * NC + lane]; }
        const float4* er = (const float4*)&e4[(size_t)ej * DOUT];
        float dot = 0.f;
#pragma unroll
        for (int c0 = 0; c0 < 32; c0 += 8) {
            float4 ev[8];
#pragma unroll
            for (int k = 0; k < 8; ++k) ev[k] = er[c0 + k];
#pragma unroll
            for (int k = 0; k < 8; ++k) {
                const float4 xc = *(const float4*)&sx[w][(c0 + k) * 4];
                dot = fmaf(ev[k].x, xc.x, dot); dot = fmaf(ev[k].y, xc.y, dot);
                dot = fmaf(ev[k].z, xc.z, dot); dot = fmaf(ev[k].w, xc.w, dot);
            }
        }
        const float sj = (lane < deg) ? dot * TEMPR : -INFINITY;
        const float m  = wave_max64(sj);
        const float ex = (lane < deg) ? expf(sj - m) : 0.f;
        const float Z  = wave_sum64(ex);
        if (lane < deg) Tval[slot] = fmaf(EM1, vn, ex / Z);
        if (lane == 0) vArr[n] = vn;
        const float tw  = deg ? fmaf((float)deg * EM1, vn, 1.0f) : 0.f;
        const float wsn = wsArr[n];
        vxa.x = fmaf(vn,  xv.x, vxa.x); vxa.y = fmaf(vn,  xv.y, vxa.y);
        twa.x = fmaf(tw,  xv.x, twa.x); twa.y = fmaf(tw,  xv.y, twa.y);
        wsa.x = fmaf(wsn, xv.x, wsa.x); wsa.y = fmaf(wsn, xv.y, wsa.y);
    }
    __syncthreads();
    if (t < DOUT) { sVX[t] = 0.f; sTX[t] = 0.f; sWX[t] = 0.f; }
    __syncthreads();
    atomicAdd(&sVX[lane*2+0], vxa.x); atomicAdd(&sVX[lane*2+1], vxa.y);
    atomicAdd(&sTX[lane*2+0], twa.x); atomicAdd(&sTX[lane*2+1], twa.y);
    atomicAdd(&sWX[lane*2+0], wsa.x); atomicAdd(&sWX[lane*2+1], wsa.y);
    __syncthreads();
    if (t < DOUT) {
        atomicAdd(&vxg[t],  sVX[t]);
        atomicAdd(&twxg[t], sTX[t]);
        atomicAdd(&wsxg[t], sWX[t]);
    }
}

// ---------------------------------------------------------------------------
// K4: per-edge: G2[e] = vx + sum_{n in e} T[e,n] * x4[n]   (unroll-8)
// ---------------------------------------------------------------------------
__global__ __launch_bounds__(256) void k_g2(
    const int* __restrict__ degE, const int* __restrict__ csrEn,
    const float* __restrict__ Tval, const float* __restrict__ vxg,
    const float* __restrict__ x4, float* __restrict__ G2)
{
    const int t    = threadIdx.x;
    const int w    = t >> 6;
    const int lane = t & 63;
    const int e    = blockIdx.x * 4 + w;
    const int deg  = min(degE[e], EC);
    float2 acc = *(const float2*)&vxg[lane * 2];
    int j = 0;
    for (; j + 8 <= deg; j += 8) {
        int ai[8]; float bi[8]; float2 fv[8];
#pragma unroll
        for (int k = 0; k < 8; ++k) { ai[k] = csrEn[e*EC+j+k]; bi[k] = Tval[e*EC+j+k]; }
#pragma unroll
        for (int k = 0; k < 8; ++k)
            fv[k] = *(const float2*)&x4[(size_t)ai[k] * DOUT + lane * 2];
#pragma unroll
        for (int k = 0; k < 8; ++k) {
            acc.x = fmaf(bi[k], fv[k].x, acc.x); acc.y = fmaf(bi[k], fv[k].y, acc.y);
        }
    }
    for (; j < deg; ++j) {
        const int   a = csrEn[e*EC+j];
        const float b = Tval[e*EC+j];
        const float2 fv = *(const float2*)&x4[(size_t)a * DOUT + lane * 2];
        acc.x = fmaf(b, fv.x, acc.x); acc.y = fmaf(b, fv.y, acc.y);
    }
    *(float2*)&G2[(size_t)e * DOUT + lane * 2] = acc;
}

// ---------------------------------------------------------------------------
// K5: final per-node combine + elu
// ---------------------------------------------------------------------------
__global__ __launch_bounds__(256) void k_final(
    const int* __restrict__ degN, const int* __restrict__ csrNe,
    const int* __restrict__ csrNs, const float* __restrict__ Sval,
    const float* __restrict__ Tval, const float* __restrict__ vArr,
    const float* __restrict__ c2g, const float* __restrict__ csx4,
    const float* __restrict__ wsxg, const float* __restrict__ vxg,
    const float* __restrict__ twxg,
    const float* __restrict__ G1, const float* __restrict__ G2,
    float* __restrict__ out)
{
    const int t    = threadIdx.x;
    const int w    = t >> 6;
    const int lane = t & 63;
    const int n    = blockIdx.x * 4 + w;
    const int deg  = min(degN[n], NC);
    const float vn = vArr[n];
    const float c2 = *c2g;
    const float2 c4v = *(const float2*)&csx4[lane * 2];
    const float2 wsv = *(const float2*)&wsxg[lane * 2];
    const float2 vxv = *(const float2*)&vxg[lane * 2];
    const float2 twv = *(const float2*)&twxg[lane * 2];
    float2 acc;
    acc.x = fmaf(c2, c4v.x, wsv.x) + vn * fmaf((float)Ee, vxv.x, twv.x);
    acc.y = fmaf(c2, c4v.y, wsv.y) + vn * fmaf((float)Ee, vxv.y, twv.y);
    int j = 0;
    for (; j + 4 <= deg; j += 4) {
        int ei[4], si[4]; float sv[4], tv[4]; float2 g1[4], g2[4];
#pragma unroll
        for (int k = 0; k < 4; ++k) {
            ei[k] = csrNe[n*NC+j+k]; si[k] = csrNs[n*NC+j+k];
        }
#pragma unroll
        for (int k = 0; k < 4; ++k) {
            sv[k] = Sval[si[k]]; tv[k] = Tval[si[k]];
            g1[k] = *(const float2*)&G1[(size_t)ei[k] * DOUT + lane * 2];
            g2[k] = *(const float2*)&G2[(size_t)ei[k] * DOUT + lane * 2];
        }
#pragma unroll
        for (int k = 0; k < 4; ++k) {
            acc.x = fmaf(sv[k], g1[k].x, acc.x); acc.y = fmaf(sv[k], g1[k].y, acc.y);
            acc.x = fmaf(tv[k], g2[k].x, acc.x); acc.y = fmaf(tv[k], g2[k].y, acc.y);
        }
    }
    for (; j < deg; ++j) {
        const int ea = csrNe[n*NC+j];
        const int sa = csrNs[n*NC+j];
        const float sva = Sval[sa], tva = Tval[sa];
        const float2 g1a = *(const float2*)&G1[(size_t)ea * DOUT + lane * 2];
        const float2 g2a = *(const float2*)&G2[(size_t)ea * DOUT + lane * 2];
        acc.x = fmaf(sva, g1a.x, acc.x); acc.y = fmaf(sva, g1a.y, acc.y);
        acc.x = fmaf(tva, g2a.x, acc.x); acc.y = fmaf(tva, g2a.y, acc.y);
    }
    acc.x = acc.x > 0.f ? acc.x : expm1f(acc.x);
    acc.y = acc.y > 0.f ? acc.y : expm1f(acc.y);
    *(float2*)&out[(size_t)n * DOUT + lane * 2] = acc;
}

// ---------------------------------------------------------------------------
extern "C" void kernel_launch(void* const* d_in, const int* in_sizes, int n_in,
                              void* d_out, int out_size, void* d_ws, size_t ws_size,
                              hipStream_t stream)
{
    const float* x    = (const float*)d_in[0];
    const float* W    = (const float*)d_in[1];
    const float* W2   = (const float*)d_in[2];
    const float* W3   = (const float*)d_in[3];
    const float* bias = (const float*)d_in[4];
    const float* q    = (const float*)d_in[5];
    const int*   hidx = (const int*)d_in[6];
    float* out = (float*)d_out;

    char* wsp = (char*)d_ws;
    size_t o = 0;
    auto take = [&](size_t bytes) {
        size_t r = o; o += (bytes + 255) & ~(size_t)255; return r;
    };
    // --- zero-initialized region (one memset) ---
    unsigned* bitmap = (unsigned*)(wsp + take((size_t)Nn * Ee / 8));   // 4 MB
    int*   degE  = (int*)  (wsp + take((size_t)Ee * 4));
    int*   degN  = (int*)  (wsp + take((size_t)Nn * 4));
    float* wsArr = (float*)(wsp + take((size_t)Nn * 4));
    float* c2g   = (float*)(wsp + take(4));
    float* csx4  = (float*)(wsp + take(DOUT * 4));
    float* csxw  = (float*)(wsp + take(DOUT * 4));
    float* vxg   = (float*)(wsp + take(DOUT * 4));
    float* twxg  = (float*)(wsp + take(DOUT * 4));
    float* wsxg  = (float*)(wsp + take(DOUT * 4));
    const size_t zbytes = o;
    // --- fully-overwritten scratch ---
    float* x4    = (float*)(wsp + take((size_t)Nn * DOUT * 4));
    float* xw    = (float*)(wsp + take((size_t)Nn * DOUT * 4));
    float* rowv  = (float*)(wsp + take((size_t)Nn * 4));
    float* vArr  = (float*)(wsp + take((size_t)Nn * 4));
    int*   csrEn = (int*)  (wsp + take((size_t)Ee * EC * 4));
    float* Sval  = (float*)(wsp + take((size_t)Ee * EC * 4));
    float* Tval  = (float*)(wsp + take((size_t)Ee * EC * 4));
    int*   csrNe = (int*)  (wsp + take((size_t)Nn * NC * 4));
    int*   csrNs = (int*)  (wsp + take((size_t)Nn * NC * 4));
    float* G1    = (float*)(wsp + take((size_t)Ee * DOUT * 4));
    float* e4    = (float*)(wsp + take((size_t)Ee * DOUT * 4));
    float* G2    = (float*)(wsp + take((size_t)Ee * DOUT * 4));
    short* W2T   = (short*)(wsp + take((size_t)DOUT * DIN * 2));   // bf16 [n][k]
    short* WWT   = (short*)(wsp + take((size_t)DOUT * DIN * 2));   // bf16 [c][r]
    float* bW3   = (float*)(wsp + take(DOUT * 4));
    (void)ws_size; (void)in_sizes; (void)n_in; (void)out_size;

    hipMemsetAsync(d_ws, 0, zbytes, stream);

    k_ww3   <<<41,      256, 0, stream>>>(W, W2, W3, bias, W2T, WWT, bW3);
    k_gemm1f<<<Nn / 16, 256, 0, stream>>>(x, W2T, WWT, bW3, q, hidx,
                                          bitmap, degE, degN, csrEn, csrNe, csrNs,
                                          x4, xw, rowv, csx4, csxw);
    k_edge1 <<<Ee / 4,  256, 0, stream>>>(degE, csrEn, rowv, csx4, csxw,
                                          x4, xw, Sval, e4, G1, wsArr, c2g);
    k_node2 <<<Nn / 8,  256, 0, stream>>>(degN, csrNe, csrNs, x4, e4, wsArr,
                                          Tval, vArr, vxg, twxg, wsxg);
    k_g2    <<<Ee / 4,  256, 0, stream>>>(degE, csrEn, Tval, vxg, x4, G2);
    k_final <<<Nn / 4,  256, 0, stream>>>(degN, csrNe, csrNs, Sval, Tval, vArr,
                                          c2g, csx4, wsxg, vxg, twxg, G1, G2, out);
}

// Round 7
// 185.354 us; speedup vs baseline: 2.3165x; 1.0729x over previous
//
#include <hip/hip_runtime.h>
#include <math.h>

// Problem constants (match reference)
constexpr int Nn   = 8192;
constexpr int Ee   = 4096;
constexpr int DIN  = 256;
constexpr int DOUT = 128;
constexpr int NNZ  = 65536;
constexpr int EC   = 96;   // capacity: nodes per edge (deg ~ Poisson(16))
constexpr int NC   = 48;   // capacity: edges per node (deg ~ Poisson(8))

#define TEMPR 0.08838834764831845f   // 1/sqrt(128)
#define EM1   1.7182818284590452f    // e - 1

typedef __attribute__((ext_vector_type(8))) short short8;
typedef __attribute__((ext_vector_type(4))) float f32x4;

static __device__ __forceinline__ float wave_sum64(float v) {
#pragma unroll
    for (int m = 32; m; m >>= 1) v += __shfl_xor(v, m, 64);
    return v;
}
static __device__ __forceinline__ float wave_max64(float v) {
#pragma unroll
    for (int m = 32; m; m >>= 1) v = fmaxf(v, __shfl_xor(v, m, 64));
    return v;
}
static __device__ __forceinline__ short f2bf(float f) {
    union { float f; unsigned u; } v; v.f = f;
    const unsigned r = (v.u + 0x7FFFu + ((v.u >> 16) & 1u)) >> 16;
    return (short)r;
}
static __device__ __forceinline__ unsigned packbf2(float a, float b) {
    return ((unsigned)(unsigned short)f2bf(a)) |
           (((unsigned)(unsigned short)f2bf(b)) << 16);
}
static __device__ __forceinline__ float2 unpackbf2(unsigned u) {
    union { unsigned u; float f; } lo, hi;
    lo.u = u << 16; hi.u = u & 0xFFFF0000u;
    return make_float2(lo.f, hi.f);
}

// ---------------------------------------------------------------------------
// K0: prologue.
//  blocks 0..31 : WW3 = W @ W3  (256x128), written transposed-bf16 WWT[c][r]
//  blocks 32..39: W2 transpose-bf16  W2T[n][k]
//  block  40    : bW3 = bias @ W3  (fp32)
// ---------------------------------------------------------------------------
__global__ __launch_bounds__(256) void k_ww3(
    const float* __restrict__ W, const float* __restrict__ W2,
    const float* __restrict__ W3, const float* __restrict__ bias,
    short* __restrict__ W2T, short* __restrict__ WWT, float* __restrict__ bW3)
{
    const int b = blockIdx.x;
    const int t = threadIdx.x;
    if (b < 32) {
        __shared__ float sW[8][128];
        const int r0 = b * 8;
        for (int i = t; i < 1024; i += 256)
            sW[i >> 7][i & 127] = W[(size_t)(r0 + (i >> 7)) * DOUT + (i & 127)];
        __syncthreads();
        const int c  = t & 127;
        const int rh = (t >> 7) * 4;
        float acc[4] = {0.f, 0.f, 0.f, 0.f};
        for (int k = 0; k < 128; ++k) {
            const float w3 = W3[(size_t)k * DOUT + c];
#pragma unroll
            for (int i = 0; i < 4; ++i) acc[i] = fmaf(sW[rh + i][k], w3, acc[i]);
        }
#pragma unroll
        for (int i = 0; i < 4; ++i)
            WWT[(size_t)c * DIN + (r0 + rh + i)] = f2bf(acc[i]);
    } else if (b < 40) {
        const int k0 = (b - 32) * 32;
        for (int i = t; i < 32 * 128; i += 256) {
            const int k = k0 + (i >> 7);
            const int n = i & 127;
            W2T[(size_t)n * DIN + k] = f2bf(W2[(size_t)k * DOUT + n]);
        }
    } else {
        if (t < 128) {
            float acc = 0.f;
            for (int k = 0; k < 128; ++k)
                acc = fmaf(bias[k], W3[(size_t)k * DOUT + t], acc);
            bW3[t] = acc;
        }
    }
}

// ---------------------------------------------------------------------------
// K1: MFMA GEMM  x4 = x@W2, xw = x@WW3 + bW3  -> bf16 arrays x4b/xwb
//     + CSR build + fp32 epilogues (rowv from exact accumulators, colsums).
// ---------------------------------------------------------------------------
__global__ __launch_bounds__(256) void k_gemm1f(
    const float* __restrict__ x, const short* __restrict__ W2T,
    const short* __restrict__ WWT, const float* __restrict__ bW3,
    const float* __restrict__ q, const int* __restrict__ hidx,
    unsigned* __restrict__ bitmap, int* __restrict__ degE, int* __restrict__ degN,
    int* __restrict__ csrEn, int* __restrict__ csrNe, int* __restrict__ csrNs,
    short* __restrict__ x4b, short* __restrict__ xwb,
    float* __restrict__ rowv, float* __restrict__ csx4, float* __restrict__ csxw)
{
    __shared__ float s4[DOUT], sw[DOUT], srow[16];
    const int t    = threadIdx.x;
    const int lane = t & 63;
    const int wv   = t >> 6;
    const int n16  = lane & 15;
    const int quad = lane >> 4;
    const int r0   = blockIdx.x * 16;
    const int n0   = wv * 32;

    // ---- CSR build ----
    const unsigned gid = blockIdx.x * 256 + t;
    if (gid < NNZ) {
        const int n = hidx[gid];
        const int e = hidx[NNZ + gid];
        const unsigned word = (unsigned)n * (unsigned)Ee + (unsigned)e;
        const unsigned bit  = 1u << (word & 31u);
        const unsigned old  = atomicOr(&bitmap[word >> 5], bit);
        if (!(old & bit)) {
            const int pe = atomicAdd(&degE[e], 1);
            if (pe < EC) {
                csrEn[e * EC + pe] = n;
                const int pn = atomicAdd(&degN[n], 1);
                if (pn < NC) {
                    csrNe[n * NC + pn] = e;
                    csrNs[n * NC + pn] = e * EC + pe;
                }
            }
        }
    }

    // ---- MFMA main loop ----
    f32x4 acc4[2], accw[2];
#pragma unroll
    for (int nt = 0; nt < 2; ++nt) {
        acc4[nt] = (f32x4){0.f, 0.f, 0.f, 0.f};
        accw[nt] = (f32x4){0.f, 0.f, 0.f, 0.f};
    }
#pragma unroll
    for (int k0 = 0; k0 < DIN; k0 += 32) {
        const int kb = k0 + quad * 8;
        const float4 xa = *(const float4*)&x[(size_t)(r0 + n16) * DIN + kb];
        const float4 xb = *(const float4*)&x[(size_t)(r0 + n16) * DIN + kb + 4];
        short8 af;
        af[0] = f2bf(xa.x); af[1] = f2bf(xa.y); af[2] = f2bf(xa.z); af[3] = f2bf(xa.w);
        af[4] = f2bf(xb.x); af[5] = f2bf(xb.y); af[6] = f2bf(xb.z); af[7] = f2bf(xb.w);
#pragma unroll
        for (int nt = 0; nt < 2; ++nt) {
            const int col = n0 + nt * 16 + n16;
            const short8 b4 = *(const short8*)&W2T[(size_t)col * DIN + kb];
            const short8 bw = *(const short8*)&WWT[(size_t)col * DIN + kb];
            acc4[nt] = __builtin_amdgcn_mfma_f32_16x16x32_bf16(af, b4, acc4[nt], 0, 0, 0);
            accw[nt] = __builtin_amdgcn_mfma_f32_16x16x32_bf16(af, bw, accw[nt], 0, 0, 0);
        }
    }

    // ---- writeback (bf16) + epilogues (fp32) ----
    float bwv[2], qv[2];
#pragma unroll
    for (int nt = 0; nt < 2; ++nt) {
        const int col = n0 + nt * 16 + n16;
        bwv[nt] = bW3[col];
        qv[nt]  = q[col];
    }
#pragma unroll
    for (int nt = 0; nt < 2; ++nt) {
        const int col = n0 + nt * 16 + n16;
#pragma unroll
        for (int reg = 0; reg < 4; ++reg) {
            const int row = r0 + quad * 4 + reg;
            x4b[(size_t)row * DOUT + col] = f2bf(acc4[nt][reg]);
            xwb[(size_t)row * DOUT + col] = f2bf(accw[nt][reg] + bwv[nt]);
        }
    }
    float pr[4];
#pragma unroll
    for (int reg = 0; reg < 4; ++reg)
        pr[reg] = qv[0] * acc4[0][reg] + qv[1] * acc4[1][reg];
#pragma unroll
    for (int m = 8; m; m >>= 1) {
#pragma unroll
        for (int reg = 0; reg < 4; ++reg) pr[reg] += __shfl_xor(pr[reg], m, 64);
    }
    if (t < 16) srow[t] = 0.f;
    if (t < DOUT) { s4[t] = 0.f; sw[t] = 0.f; }
    __syncthreads();
    if (n16 == 0) {
#pragma unroll
        for (int reg = 0; reg < 4; ++reg) atomicAdd(&srow[quad * 4 + reg], pr[reg]);
    }
#pragma unroll
    for (int nt = 0; nt < 2; ++nt) {
        const int col = n0 + nt * 16 + n16;
        const float c4s = acc4[nt][0] + acc4[nt][1] + acc4[nt][2] + acc4[nt][3];
        const float cws = accw[nt][0] + accw[nt][1] + accw[nt][2] + accw[nt][3]
                        + 4.f * bwv[nt];
        atomicAdd(&s4[col], c4s);
        atomicAdd(&sw[col], cws);
    }
    __syncthreads();
    if (t < 16) rowv[r0 + t] = srow[t] * TEMPR;
    if (t < DOUT) { atomicAdd(&csx4[t], s4[t]); atomicAdd(&csxw[t], sw[t]); }
}

// ---------------------------------------------------------------------------
// K2: per-edge: softmax1 -> Sval + ws scatter + c2; gathers (bf16, 1 dword/lane)
//     e4b = att1 @ xw  (bf16 out),  G1b = att1 @ x4  (bf16 out)
// ---------------------------------------------------------------------------
__global__ __launch_bounds__(256) void k_edge1(
    const int* __restrict__ degE, const int* __restrict__ csrEn,
    const float* __restrict__ rowv,
    const float* __restrict__ csx4, const float* __restrict__ csxw,
    const unsigned* __restrict__ x4b, const unsigned* __restrict__ xwb,
    float* __restrict__ Sval, unsigned* __restrict__ e4b, unsigned* __restrict__ G1b,
    float* __restrict__ wsArr, float* __restrict__ c2g)
{
    __shared__ int   sN[4][EC];
    __shared__ float sS[4][EC];
    __shared__ float sC2[4];
    const int t    = threadIdx.x;
    const int w    = t >> 6;
    const int lane = t & 63;
    const int e    = blockIdx.x * 4 + w;
    const int deg  = min(degE[e], EC);
    const float ue = deg ? 1.0f / ((float)Nn + (float)deg * EM1) : 2.0f / (float)Nn;

    int   n0 = 0, n1 = 0;
    float r0 = -INFINITY, r1 = -INFINITY;
    if (lane < deg)      { n0 = csrEn[e * EC + lane];      r0 = rowv[n0]; }
    if (lane + 64 < deg) { n1 = csrEn[e * EC + lane + 64]; r1 = rowv[n1]; }
    const float m  = wave_max64(fmaxf(r0, r1));
    const float e0 = (lane < deg)      ? expf(r0 - m) : 0.f;
    const float e1 = (lane + 64 < deg) ? expf(r1 - m) : 0.f;
    const float Z  = wave_sum64(e0 + e1);
    const float inv = deg ? 1.0f / Z : 0.f;
    const float base = EM1 * ue;
    if (lane < deg) {
        const float sv = fmaf(e0, inv, base);
        sN[w][lane] = n0; sS[w][lane] = sv;
        Sval[e * EC + lane] = sv;
        atomicAdd(&wsArr[n0], ue * sv);
    }
    if (lane + 64 < deg) {
        const float sv = fmaf(e1, inv, base);
        sN[w][lane + 64] = n1; sS[w][lane + 64] = sv;
        Sval[e * EC + lane + 64] = sv;
        atomicAdd(&wsArr[n1], ue * sv);
    }

    const float2 cw = *(const float2*)&csxw[lane * 2];
    const float2 c4 = *(const float2*)&csx4[lane * 2];
    float2 aE = make_float2(ue * cw.x, ue * cw.y);
    float2 aG = make_float2(ue * c4.x, ue * c4.y);
    int j = 0;
    for (; j + 8 <= deg; j += 8) {
        int ai[8]; float bi[8]; unsigned tu[8], fu[8];
#pragma unroll
        for (int k = 0; k < 8; ++k) { ai[k] = sN[w][j+k]; bi[k] = sS[w][j+k]; }
#pragma unroll
        for (int k = 0; k < 8; ++k) {
            tu[k] = xwb[(size_t)ai[k] * 64 + lane];
            fu[k] = x4b[(size_t)ai[k] * 64 + lane];
        }
#pragma unroll
        for (int k = 0; k < 8; ++k) {
            const float2 tv = unpackbf2(tu[k]);
            const float2 fv = unpackbf2(fu[k]);
            aE.x = fmaf(bi[k], tv.x, aE.x); aE.y = fmaf(bi[k], tv.y, aE.y);
            aG.x = fmaf(bi[k], fv.x, aG.x); aG.y = fmaf(bi[k], fv.y, aG.y);
        }
    }
    for (; j < deg; ++j) {
        const int   a = sN[w][j];
        const float b = sS[w][j];
        const float2 tv = unpackbf2(xwb[(size_t)a * 64 + lane]);
        const float2 fv = unpackbf2(x4b[(size_t)a * 64 + lane]);
        aE.x = fmaf(b, tv.x, aE.x); aE.y = fmaf(b, tv.y, aE.y);
        aG.x = fmaf(b, fv.x, aG.x); aG.y = fmaf(b, fv.y, aG.y);
    }
    e4b[(size_t)e * 64 + lane] = packbf2(aE.x, aE.y);
    G1b[(size_t)e * 64 + lane] = packbf2(aG.x, aG.y);

    if (lane == 0) sC2[w] = ue * ue;
    __syncthreads();
    if (t == 0) atomicAdd(c2g, sC2[0] + sC2[1] + sC2[2] + sC2[3]);
}

// ---------------------------------------------------------------------------
// K3: per-node softmax2 (lane-per-edge streaming dots over bf16 e4b rows)
//     -> Tval, v[n]; weighted colsum epilogues.
// ---------------------------------------------------------------------------
__global__ __launch_bounds__(256) void k_node2(
    const int* __restrict__ degN, const int* __restrict__ csrNe,
    const int* __restrict__ csrNs, const unsigned* __restrict__ x4b,
    const unsigned* __restrict__ e4b, const float* __restrict__ wsArr,
    float* __restrict__ Tval, float* __restrict__ vArr,
    float* __restrict__ vxg, float* __restrict__ twxg, float* __restrict__ wsxg)
{
    __shared__ float sx[4][DOUT];
    __shared__ float sVX[DOUT], sTX[DOUT], sWX[DOUT];
    const int t    = threadIdx.x;
    const int w    = t >> 6;
    const int lane = t & 63;

    float2 vxa = {0,0}, twa = {0,0}, wsa = {0,0};
#pragma unroll
    for (int s = 0; s < 2; ++s) {
        const int n   = blockIdx.x * 8 + w * 2 + s;
        const int deg = min(degN[n], NC);
        const float vn = deg ? 1.0f / ((float)Ee + (float)deg * EM1) : 2.0f / (float)Ee;
        const float2 xv = unpackbf2(x4b[(size_t)n * 64 + lane]);
        __syncthreads();
        sx[w][lane * 2 + 0] = xv.x;
        sx[w][lane * 2 + 1] = xv.y;
        __syncthreads();
        int ej = 0, slot = 0;
        if (lane < deg) { ej = csrNe[n * NC + lane]; slot = csrNs[n * NC + lane]; }
        const uint4* er = (const uint4*)&e4b[(size_t)ej * 64];   // 16 x uint4
        float dot = 0.f;
#pragma unroll
        for (int c0 = 0; c0 < 16; c0 += 8) {
            uint4 ev[8];
#pragma unroll
            for (int k = 0; k < 8; ++k) ev[k] = er[c0 + k];
#pragma unroll
            for (int k = 0; k < 8; ++k) {
                const int base = (c0 + k) * 8;
                const float2 e0 = unpackbf2(ev[k].x);
                const float2 e1 = unpackbf2(ev[k].y);
                const float2 e2 = unpackbf2(ev[k].z);
                const float2 e3 = unpackbf2(ev[k].w);
                dot = fmaf(e0.x, sx[w][base + 0], dot);
                dot = fmaf(e0.y, sx[w][base + 1], dot);
                dot = fmaf(e1.x, sx[w][base + 2], dot);
                dot = fmaf(e1.y, sx[w][base + 3], dot);
                dot = fmaf(e2.x, sx[w][base + 4], dot);
                dot = fmaf(e2.y, sx[w][base + 5], dot);
                dot = fmaf(e3.x, sx[w][base + 6], dot);
                dot = fmaf(e3.y, sx[w][base + 7], dot);
            }
        }
        const float sj = (lane < deg) ? dot * TEMPR : -INFINITY;
        const float m  = wave_max64(sj);
        const float ex = (lane < deg) ? expf(sj - m) : 0.f;
        const float Z  = wave_sum64(ex);
        if (lane < deg) Tval[slot] = fmaf(EM1, vn, ex / Z);
        if (lane == 0) vArr[n] = vn;
        const float tw  = deg ? fmaf((float)deg * EM1, vn, 1.0f) : 0.f;
        const float wsn = wsArr[n];
        vxa.x = fmaf(vn,  xv.x, vxa.x); vxa.y = fmaf(vn,  xv.y, vxa.y);
        twa.x = fmaf(tw,  xv.x, twa.x); twa.y = fmaf(tw,  xv.y, twa.y);
        wsa.x = fmaf(wsn, xv.x, wsa.x); wsa.y = fmaf(wsn, xv.y, wsa.y);
    }
    __syncthreads();
    if (t < DOUT) { sVX[t] = 0.f; sTX[t] = 0.f; sWX[t] = 0.f; }
    __syncthreads();
    atomicAdd(&sVX[lane*2+0], vxa.x); atomicAdd(&sVX[lane*2+1], vxa.y);
    atomicAdd(&sTX[lane*2+0], twa.x); atomicAdd(&sTX[lane*2+1], twa.y);
    atomicAdd(&sWX[lane*2+0], wsa.x); atomicAdd(&sWX[lane*2+1], wsa.y);
    __syncthreads();
    if (t < DOUT) {
        atomicAdd(&vxg[t],  sVX[t]);
        atomicAdd(&twxg[t], sTX[t]);
        atomicAdd(&wsxg[t], sWX[t]);
    }
}

// ---------------------------------------------------------------------------
// K4: per-edge: G2b[e] = vx + sum_{n in e} T[e,n] * x4[n]   (bf16 gather)
// ---------------------------------------------------------------------------
__global__ __launch_bounds__(256) void k_g2(
    const int* __restrict__ degE, const int* __restrict__ csrEn,
    const float* __restrict__ Tval, const float* __restrict__ vxg,
    const unsigned* __restrict__ x4b, unsigned* __restrict__ G2b)
{
    const int t    = threadIdx.x;
    const int w    = t >> 6;
    const int lane = t & 63;
    const int e    = blockIdx.x * 4 + w;
    const int deg  = min(degE[e], EC);
    float2 acc = *(const float2*)&vxg[lane * 2];
    int j = 0;
    for (; j + 8 <= deg; j += 8) {
        int ai[8]; float bi[8]; unsigned fu[8];
#pragma unroll
        for (int k = 0; k < 8; ++k) { ai[k] = csrEn[e*EC+j+k]; bi[k] = Tval[e*EC+j+k]; }
#pragma unroll
        for (int k = 0; k < 8; ++k)
            fu[k] = x4b[(size_t)ai[k] * 64 + lane];
#pragma unroll
        for (int k = 0; k < 8; ++k) {
            const float2 fv = unpackbf2(fu[k]);
            acc.x = fmaf(bi[k], fv.x, acc.x); acc.y = fmaf(bi[k], fv.y, acc.y);
        }
    }
    for (; j < deg; ++j) {
        const int   a = csrEn[e*EC+j];
        const float b = Tval[e*EC+j];
        const float2 fv = unpackbf2(x4b[(size_t)a * 64 + lane]);
        acc.x = fmaf(b, fv.x, acc.x); acc.y = fmaf(b, fv.y, acc.y);
    }
    G2b[(size_t)e * 64 + lane] = packbf2(acc.x, acc.y);
}

// ---------------------------------------------------------------------------
// K5: final per-node combine + elu  (bf16 gathers of G1b/G2b)
// ---------------------------------------------------------------------------
__global__ __launch_bounds__(256) void k_final(
    const int* __restrict__ degN, const int* __restrict__ csrNe,
    const int* __restrict__ csrNs, const float* __restrict__ Sval,
    const float* __restrict__ Tval, const float* __restrict__ vArr,
    const float* __restrict__ c2g, const float* __restrict__ csx4,
    const float* __restrict__ wsxg, const float* __restrict__ vxg,
    const float* __restrict__ twxg,
    const unsigned* __restrict__ G1b, const unsigned* __restrict__ G2b,
    float* __restrict__ out)
{
    const int t    = threadIdx.x;
    const int w    = t >> 6;
    const int lane = t & 63;
    const int n    = blockIdx.x * 4 + w;
    const int deg  = min(degN[n], NC);
    const float vn = vArr[n];
    const float c2 = *c2g;
    const float2 c4v = *(const float2*)&csx4[lane * 2];
    const float2 wsv = *(const float2*)&wsxg[lane * 2];
    const float2 vxv = *(const float2*)&vxg[lane * 2];
    const float2 twv = *(const float2*)&twxg[lane * 2];
    float2 acc;
    acc.x = fmaf(c2, c4v.x, wsv.x) + vn * fmaf((float)Ee, vxv.x, twv.x);
    acc.y = fmaf(c2, c4v.y, wsv.y) + vn * fmaf((float)Ee, vxv.y, twv.y);
    int j = 0;
    for (; j + 4 <= deg; j += 4) {
        int ei[4], si[4]; float sv[4], tv[4]; unsigned g1u[4], g2u[4];
#pragma unroll
        for (int k = 0; k < 4; ++k) {
            ei[k] = csrNe[n*NC+j+k]; si[k] = csrNs[n*NC+j+k];
        }
#pragma unroll
        for (int k = 0; k < 4; ++k) {
            sv[k] = Sval[si[k]]; tv[k] = Tval[si[k]];
            g1u[k] = G1b[(size_t)ei[k] * 64 + lane];
            g2u[k] = G2b[(size_t)ei[k] * 64 + lane];
        }
#pragma unroll
        for (int k = 0; k < 4; ++k) {
            const float2 g1 = unpackbf2(g1u[k]);
            const float2 g2 = unpackbf2(g2u[k]);
            acc.x = fmaf(sv[k], g1.x, acc.x); acc.y = fmaf(sv[k], g1.y, acc.y);
            acc.x = fmaf(tv[k], g2.x, acc.x); acc.y = fmaf(tv[k], g2.y, acc.y);
        }
    }
    for (; j < deg; ++j) {
        const int ea = csrNe[n*NC+j];
        const int sa = csrNs[n*NC+j];
        const float sva = Sval[sa], tva = Tval[sa];
        const float2 g1a = unpackbf2(G1b[(size_t)ea * 64 + lane]);
        const float2 g2a = unpackbf2(G2b[(size_t)ea * 64 + lane]);
        acc.x = fmaf(sva, g1a.x, acc.x); acc.y = fmaf(sva, g1a.y, acc.y);
        acc.x = fmaf(tva, g2a.x, acc.x); acc.y = fmaf(tva, g2a.y, acc.y);
    }
    acc.x = acc.x > 0.f ? acc.x : expm1f(acc.x);
    acc.y = acc.y > 0.f ? acc.y : expm1f(acc.y);
    *(float2*)&out[(size_t)n * DOUT + lane * 2] = acc;
}

// ---------------------------------------------------------------------------
extern "C" void kernel_launch(void* const* d_in, const int* in_sizes, int n_in,
                              void* d_out, int out_size, void* d_ws, size_t ws_size,
                              hipStream_t stream)
{
    const float* x    = (const float*)d_in[0];
    const float* W    = (const float*)d_in[1];
    const float* W2   = (const float*)d_in[2];
    const float* W3   = (const float*)d_in[3];
    const float* bias = (const float*)d_in[4];
    const float* q    = (const float*)d_in[5];
    const int*   hidx = (const int*)d_in[6];
    float* out = (float*)d_out;

    char* wsp = (char*)d_ws;
    size_t o = 0;
    auto take = [&](size_t bytes) {
        size_t r = o; o += (bytes + 255) & ~(size_t)255; return r;
    };
    // --- zero-initialized region (one memset) ---
    unsigned* bitmap = (unsigned*)(wsp + take((size_t)Nn * Ee / 8));   // 4 MB
    int*   degE  = (int*)  (wsp + take((size_t)Ee * 4));
    int*   degN  = (int*)  (wsp + take((size_t)Nn * 4));
    float* wsArr = (float*)(wsp + take((size_t)Nn * 4));
    float* c2g   = (float*)(wsp + take(4));
    float* csx4  = (float*)(wsp + take(DOUT * 4));
    float* csxw  = (float*)(wsp + take(DOUT * 4));
    float* vxg   = (float*)(wsp + take(DOUT * 4));
    float* twxg  = (float*)(wsp + take(DOUT * 4));
    float* wsxg  = (float*)(wsp + take(DOUT * 4));
    const size_t zbytes = o;
    // --- fully-overwritten scratch ---
    short* x4b   = (short*)(wsp + take((size_t)Nn * DOUT * 2));   // bf16
    short* xwb   = (short*)(wsp + take((size_t)Nn * DOUT * 2));   // bf16
    float* rowv  = (float*)(wsp + take((size_t)Nn * 4));
    float* vArr  = (float*)(wsp + take((size_t)Nn * 4));
    int*   csrEn = (int*)  (wsp + take((size_t)Ee * EC * 4));
    float* Sval  = (float*)(wsp + take((size_t)Ee * EC * 4));
    float* Tval  = (float*)(wsp + take((size_t)Ee * EC * 4));
    int*   csrNe = (int*)  (wsp + take((size_t)Nn * NC * 4));
    int*   csrNs = (int*)  (wsp + take((size_t)Nn * NC * 4));
    unsigned* e4b = (unsigned*)(wsp + take((size_t)Ee * DOUT * 2));   // bf16
    unsigned* G1b = (unsigned*)(wsp + take((size_t)Ee * DOUT * 2));   // bf16
    unsigned* G2b = (unsigned*)(wsp + take((size_t)Ee * DOUT * 2));   // bf16
    short* W2T   = (short*)(wsp + take((size_t)DOUT * DIN * 2));   // bf16 [n][k]
    short* WWT   = (short*)(wsp + take((size_t)DOUT * DIN * 2));   // bf16 [c][r]
    float* bW3   = (float*)(wsp + take(DOUT * 4));
    (void)ws_size; (void)in_sizes; (void)n_in; (void)out_size;

    hipMemsetAsync(d_ws, 0, zbytes, stream);

    k_ww3   <<<41,      256, 0, stream>>>(W, W2, W3, bias, W2T, WWT, bW3);
    k_gemm1f<<<Nn / 16, 256, 0, stream>>>(x, W2T, WWT, bW3, q, hidx,
                                          bitmap, degE, degN, csrEn, csrNe, csrNs,
                                          x4b, xwb, rowv, csx4, csxw);
    k_edge1 <<<Ee / 4,  256, 0, stream>>>(degE, csrEn, rowv, csx4, csxw,
                                          (const unsigned*)x4b, (const unsigned*)xwb,
                                          Sval, e4b, G1b, wsArr, c2g);
    k_node2 <<<Nn / 8,  256, 0, stream>>>(degN, csrNe, csrNs,
                                          (const unsigned*)x4b, e4b, wsArr,
                                          Tval, vArr, vxg, twxg, wsxg);
    k_g2    <<<Ee / 4,  256, 0, stream>>>(degE, csrEn, Tval, vxg,
                                          (const unsigned*)x4b, G2b);
    k_final <<<Nn / 4,  256, 0, stream>>>(degN, csrNe, csrNs, Sval, Tval, vArr,
                                          c2g, csx4, wsxg, vxg, twxg, G1b, G2b, out);
}